// Round 6
// baseline (647.993 us; speedup 1.0000x reference)
//
#include <hip/hip_runtime.h>
#include <hip/hip_cooperative_groups.h>
#include <math.h>

namespace cg = cooperative_groups;

// ---------------------------------------------------------------------------
// GraphTransformerLayer N=50000, E=640000, D=128, H=8, DH=16  (gfx950)
// Round 6: round-5 pipeline (f16 MFMA GEMMs, fragment-ordered layouts,
// fdot2 attention, fused cooperative CSR build, parallel BN1 fold) with the
// k_fold1b grid bug fixed: W1 has 2*D=256 output rows -> 256 blocks, not 128.
//
// Fragment order for an MxK slab (M=128, K=KB*32):
//   elem index = ((kb*8 + mtile)*64 + lane)*8 + j
//   row = mtile*16 + (lane&15),  col = kb*32 + (lane>>4)*8 + j
// MFMA 16x16x32 f16: A[m=lane&15][k=(lane>>4)*8+j]; C/D: col=lane&15,
// row=(lane>>4)*4+reg.
// ---------------------------------------------------------------------------

#define ND128 16384
typedef _Float16 f16;
typedef __attribute__((ext_vector_type(8))) _Float16 h8;
typedef __attribute__((ext_vector_type(2))) _Float16 h2;
typedef __attribute__((ext_vector_type(4))) float f4;

// --- cast h (fp32 row-major) -> hb (f16 fragment order, zero-padded rows) --
__global__ __launch_bounds__(256) void k_cast_h(
    const float* __restrict__ h, f16* __restrict__ hb, int N)
{
    const int slab = blockIdx.x;
    const int tid = threadIdx.x;
#pragma unroll
    for (int it = 0; it < 8; ++it) {
        int cid = it * 256 + tid;              // 0..2047
        int lane = cid & 63;
        int m = (cid >> 6) & 7;
        int kb = cid >> 9;
        int row = slab * 128 + m * 16 + (lane & 15);
        int col = kb * 32 + (lane >> 4) * 8;
        f16 o8[8];
        if (row < N) {
            const float* p = h + (size_t)row * 128 + col;
            float4 f0 = *(const float4*)p;
            float4 f1 = *(const float4*)(p + 4);
            o8[0] = (f16)f0.x; o8[1] = (f16)f0.y; o8[2] = (f16)f0.z; o8[3] = (f16)f0.w;
            o8[4] = (f16)f1.x; o8[5] = (f16)f1.y; o8[6] = (f16)f1.z; o8[7] = (f16)f1.w;
        } else {
#pragma unroll
            for (int j = 0; j < 8; ++j) o8[j] = (f16)0.f;
        }
        *(h8*)(hb + (size_t)slab * ND128 + (size_t)cid * 8) = *(const h8*)o8;
    }
}

// --- cast weights -> f16 fragment order; block 0 also zeroes bn. -----------
__global__ __launch_bounds__(256) void k_cast_w(
    const float* __restrict__ WQ, const float* __restrict__ WK,
    const float* __restrict__ WV, const float* __restrict__ WO,
    const float* __restrict__ W2,
    f16* __restrict__ Wqb, f16* __restrict__ Wkb,
    f16* __restrict__ Wvb, f16* __restrict__ Wob, f16* __restrict__ W2b,
    float* __restrict__ bn)
{
    const int b = blockIdx.x;
    if (b == 0) { bn[threadIdx.x] = 0.f; bn[threadIdx.x + 256] = 0.f; }
    const float* Wsrc; f16* dst; int K, base;
    if (b < 4) {
        Wsrc = b == 0 ? WQ : b == 1 ? WK : b == 2 ? WV : WO;
        dst  = b == 0 ? Wqb : b == 1 ? Wkb : b == 2 ? Wvb : Wob;
        K = 128; base = 0;
    } else {
        Wsrc = W2; dst = W2b; K = 256; base = (b - 4) * 2048;
    }
#pragma unroll
    for (int it = 0; it < 8; ++it) {
        int cid = base + it * 256 + threadIdx.x;
        int lane = cid & 63;
        int kb, nt;
        if (K == 128) { kb = (cid >> 6) & 3; nt = cid >> 8; }
        else          { kb = (cid >> 6) & 7; nt = cid >> 9; }
        int row = nt * 16 + (lane & 15);
        int col = kb * 32 + (lane >> 4) * 8;
        const float* p = Wsrc + (size_t)row * K + col;
        f16 o8[8];
#pragma unroll
        for (int j = 0; j < 8; ++j) o8[j] = (f16)p[j];
        *(h8*)(dst + (size_t)cid * 8) = *(const h8*)o8;
    }
}

// --- QKV: out = hb @ Wb^T, f16 row-major outputs.  grid (slabs, 3) ---------
__global__ __launch_bounds__(256) void k_qkv(
    const f16* __restrict__ hb, const f16* __restrict__ Wqb,
    const f16* __restrict__ Wkb, const f16* __restrict__ Wvb,
    f16* __restrict__ Qb, f16* __restrict__ Kb, f16* __restrict__ Vb, int N)
{
    const int slab = blockIdx.x;
    const int w = threadIdx.x >> 6, lane = threadIdx.x & 63;
    const f16* __restrict__ Wb = blockIdx.y == 0 ? Wqb : blockIdx.y == 1 ? Wkb : Wvb;
    f16* __restrict__ Ob = blockIdx.y == 0 ? Qb : blockIdx.y == 1 ? Kb : Vb;
    const f16* A = hb + (size_t)slab * ND128;

    h8 bfr[2][4];
#pragma unroll
    for (int nt = 0; nt < 2; ++nt)
#pragma unroll
        for (int kb = 0; kb < 4; ++kb)
            bfr[nt][kb] = *(const h8*)(Wb + (size_t)(((2 * w + nt) * 4 + kb) * 64 + lane) * 8);

    f4 acc[8][2];
    f4 zero = {0.f, 0.f, 0.f, 0.f};
#pragma unroll
    for (int m = 0; m < 8; ++m) { acc[m][0] = zero; acc[m][1] = zero; }

#pragma unroll
    for (int m = 0; m < 8; ++m) {
#pragma unroll
        for (int kb = 0; kb < 4; ++kb) {
            h8 a = *(const h8*)(A + (size_t)((kb * 8 + m) * 64 + lane) * 8);
            acc[m][0] = __builtin_amdgcn_mfma_f32_16x16x32_f16(a, bfr[0][kb], acc[m][0], 0, 0, 0);
            acc[m][1] = __builtin_amdgcn_mfma_f32_16x16x32_f16(a, bfr[1][kb], acc[m][1], 0, 0, 0);
        }
    }

    const int c = lane & 15, quad = lane >> 4;
#pragma unroll
    for (int m = 0; m < 8; ++m)
#pragma unroll
        for (int nt = 0; nt < 2; ++nt) {
            int col = w * 32 + nt * 16 + c;
#pragma unroll
            for (int r = 0; r < 4; ++r) {
                int gr = slab * 128 + m * 16 + quad * 4 + r;
                if (gr < N) Ob[(size_t)gr * 128 + col] = (f16)acc[m][nt][r];
            }
        }
}

// --- fused CSR build: zero cursor -> hist -> 2-level scan -> scatter. ------
// 512 blocks x 256 threads, cooperative (grid.sync between phases).
__global__ __launch_bounds__(256) void k_csr(
    const int* __restrict__ src, const int* __restrict__ dst,
    int* __restrict__ cursor, int* __restrict__ rowptr, int* __restrict__ csr_src,
    int* __restrict__ bsum, int* __restrict__ boff, int N, int E)
{
    cg::grid_group grid = cg::this_grid();
    const int t = threadIdx.x, b = blockIdx.x, nb = gridDim.x;
    const int gsz = nb * 256;
    const int gt = b * 256 + t;
    __shared__ int part[256];
    __shared__ int p2[256];

    // phase 0: zero cursor
    for (int i = gt; i < N; i += gsz) cursor[i] = 0;
    grid.sync();
    // phase 1: histogram
    for (int e = gt; e < E; e += gsz) atomicAdd(&cursor[dst[e]], 1);
    grid.sync();
    // phase 2: block-local exclusive scan of chunk (chunk <= 256)
    const int chunk = (N + nb - 1) / nb;
    const int idx = b * chunk + t;
    const bool act = (t < chunk) && (idx < N);
    int v = act ? cursor[idx] : 0;
    part[t] = v;
    __syncthreads();
    for (int off = 1; off < 256; off <<= 1) {
        int pv = (t >= off) ? part[t - off] : 0;
        __syncthreads();
        part[t] += pv;
        __syncthreads();
    }
    if (t == 0) bsum[b] = part[255];
    if (act) rowptr[idx] = part[t] - v;     // local prefix, fixed up in phase 4
    grid.sync();
    // phase 3: block 0 scans the nb (=512) block sums, 2 per thread
    if (b == 0) {
        int s0 = bsum[2 * t], s1 = bsum[2 * t + 1];
        int pr = s0 + s1;
        p2[t] = pr;
        __syncthreads();
        for (int off = 1; off < 256; off <<= 1) {
            int pv = (t >= off) ? p2[t - off] : 0;
            __syncthreads();
            p2[t] += pv;
            __syncthreads();
        }
        int e0 = p2[t] - pr;
        boff[2 * t] = e0;
        boff[2 * t + 1] = e0 + s0;
        if (t == 255) rowptr[N] = p2[255];
    }
    grid.sync();
    // phase 4: add block offset -> final rowptr & cursor
    if (act) {
        int r = rowptr[idx] + boff[b];
        rowptr[idx] = r;
        cursor[idx] = r;
    }
    grid.sync();
    // phase 5: scatter src ids into per-dst segments
    for (int e = gt; e < E; e += gsz) {
        int pos = atomicAdd(&cursor[dst[e]], 1);
        csr_src[pos] = src[e];
    }
}

// --- attention: one wave per node, lane owns channels (2l, 2l+1). ----------
// f16: dot via v_dot2_f32_f16, accumulate via packed h2 fma.
__global__ __launch_bounds__(256) void k_attn(
    const f16* __restrict__ Qb, const f16* __restrict__ Kb,
    const f16* __restrict__ Vb,
    const int* __restrict__ rowptr, const int* __restrict__ csr_src,
    f16* __restrict__ attnf, int N)
{
    const int node = blockIdx.x * 4 + (threadIdx.x >> 6);
    const int lane = threadIdx.x & 63;
    if (node >= N) return;
    const int beg = rowptr[node], end = rowptr[node + 1];
    const h2 q2 = ((const h2*)(Qb + (size_t)node * 128))[lane];
    h2 acc2 = {(f16)0.f, (f16)0.f};
    float z = 0.f;
    int i = beg;
    for (; i + 1 < end; i += 2) {
        int s0 = csr_src[i], s1 = csr_src[i + 1];
        h2 k0 = ((const h2*)(Kb + (size_t)s0 * 128))[lane];
        h2 v0 = ((const h2*)(Vb + (size_t)s0 * 128))[lane];
        h2 k1 = ((const h2*)(Kb + (size_t)s1 * 128))[lane];
        h2 v1 = ((const h2*)(Vb + (size_t)s1 * 128))[lane];
#if __has_builtin(__builtin_amdgcn_fdot2)
        float p0 = __builtin_amdgcn_fdot2(q2, k0, 0.f, false);
        float p1 = __builtin_amdgcn_fdot2(q2, k1, 0.f, false);
#else
        float p0 = (float)q2.x * (float)k0.x + (float)q2.y * (float)k0.y;
        float p1 = (float)q2.x * (float)k1.x + (float)q2.y * (float)k1.y;
#endif
        p0 += __shfl_xor(p0, 4, 8); p0 += __shfl_xor(p0, 2, 8); p0 += __shfl_xor(p0, 1, 8);
        p1 += __shfl_xor(p1, 4, 8); p1 += __shfl_xor(p1, 2, 8); p1 += __shfl_xor(p1, 1, 8);
        float sc0 = __expf(fminf(fmaxf(p0 * 0.25f, -5.f), 5.f));
        float sc1 = __expf(fminf(fmaxf(p1 * 0.25f, -5.f), 5.f));
        h2 s2a = {(f16)sc0, (f16)sc0};
        h2 s2b = {(f16)sc1, (f16)sc1};
        acc2 = v0 * s2a + acc2;
        acc2 = v1 * s2b + acc2;
        z += sc0 + sc1;
    }
    if (i < end) {
        int s0 = csr_src[i];
        h2 k0 = ((const h2*)(Kb + (size_t)s0 * 128))[lane];
        h2 v0 = ((const h2*)(Vb + (size_t)s0 * 128))[lane];
#if __has_builtin(__builtin_amdgcn_fdot2)
        float p0 = __builtin_amdgcn_fdot2(q2, k0, 0.f, false);
#else
        float p0 = (float)q2.x * (float)k0.x + (float)q2.y * (float)k0.y;
#endif
        p0 += __shfl_xor(p0, 4, 8); p0 += __shfl_xor(p0, 2, 8); p0 += __shfl_xor(p0, 1, 8);
        float sc0 = __expf(fminf(fmaxf(p0 * 0.25f, -5.f), 5.f));
        h2 s2a = {(f16)sc0, (f16)sc0};
        acc2 = v0 * s2a + acc2;
        z += sc0;
    }
    float inv = 1.f / z;
    h2 o2 = {(f16)((float)acc2.x * inv), (f16)((float)acc2.y * inv)};
    int slab = node >> 7, m = (node >> 4) & 7, lr = node & 15;
    int kb = lane >> 4, quad2 = (lane & 15) >> 2, j = (lane & 3) * 2;
    *(h2*)(attnf + (size_t)slab * ND128 +
           (size_t)(((kb * 8 + m) * 64 + lr + 16 * quad2) * 8 + j)) = o2;
}

// --- O-proj: t1 = attn @ WO^T + h + bO. fp32 out + f16 frag t1b + BN1 sums.
__global__ __launch_bounds__(256) void k_oproj(
    const f16* __restrict__ attnf, const f16* __restrict__ Wob,
    const float* __restrict__ h, const float* __restrict__ bO,
    float* __restrict__ out, f16* __restrict__ t1b,
    float* __restrict__ bn, int N)
{
    __shared__ float csum[128], csq[128];
    const int tid = threadIdx.x, slab = blockIdx.x;
    const int w = tid >> 6, lane = tid & 63;
    if (tid < 128) { csum[tid] = 0.f; csq[tid] = 0.f; }
    __syncthreads();
    const f16* A = attnf + (size_t)slab * ND128;

    h8 bfr[2][4];
#pragma unroll
    for (int nt = 0; nt < 2; ++nt)
#pragma unroll
        for (int kb = 0; kb < 4; ++kb)
            bfr[nt][kb] = *(const h8*)(Wob + (size_t)(((2 * w + nt) * 4 + kb) * 64 + lane) * 8);

    f4 acc[8][2];
    f4 zero = {0.f, 0.f, 0.f, 0.f};
#pragma unroll
    for (int m = 0; m < 8; ++m) { acc[m][0] = zero; acc[m][1] = zero; }
#pragma unroll
    for (int m = 0; m < 8; ++m) {
#pragma unroll
        for (int kb = 0; kb < 4; ++kb) {
            h8 a = *(const h8*)(A + (size_t)((kb * 8 + m) * 64 + lane) * 8);
            acc[m][0] = __builtin_amdgcn_mfma_f32_16x16x32_f16(a, bfr[0][kb], acc[m][0], 0, 0, 0);
            acc[m][1] = __builtin_amdgcn_mfma_f32_16x16x32_f16(a, bfr[1][kb], acc[m][1], 0, 0, 0);
        }
    }

    const int c = lane & 15, quad = lane >> 4;
    float pcs[2] = {0.f, 0.f}, pcq[2] = {0.f, 0.f};
#pragma unroll
    for (int m = 0; m < 8; ++m)
#pragma unroll
        for (int nt = 0; nt < 2; ++nt) {
            int cl = w * 32 + nt * 16 + c;
            float bo = bO[cl];
            int quad2 = nt * 2 + (c >> 3), j = c & 7;
#pragma unroll
            for (int r = 0; r < 4; ++r) {
                int rl = m * 16 + quad * 4 + r;
                int gr = slab * 128 + rl;
                if (gr < N) {
                    float v = acc[m][nt][r] + h[(size_t)gr * 128 + cl] + bo;
                    out[(size_t)gr * 128 + cl] = v;
                    t1b[(size_t)slab * ND128 +
                        (size_t)(((w * 8 + m) * 64 + quad * 4 + r + 16 * quad2) * 8 + j)] = (f16)v;
                    pcs[nt] += v; pcq[nt] += v * v;
                }
            }
        }
#pragma unroll
    for (int nt = 0; nt < 2; ++nt) {
        atomicAdd(&csum[w * 32 + nt * 16 + c], pcs[nt]);
        atomicAdd(&csq[w * 32 + nt * 16 + c], pcq[nt]);
    }
    __syncthreads();
    if (tid < 128) {
        atomicAdd(bn + tid, csum[tid]);
        atomicAdd(bn + 128 + tid, csq[tid]);
    }
}

// --- BN1 stats -> sfold/bfold (1 block, 128 threads) -----------------------
__global__ __launch_bounds__(128) void k_fold1a(
    const float* __restrict__ bn, const float* __restrict__ g1,
    const float* __restrict__ bb1,
    float* __restrict__ sfold, float* __restrict__ bfold, int N)
{
    const int tid = threadIdx.x;
    float invN = 1.f / (float)N;
    float mu = bn[tid] * invN;
    float var = bn[128 + tid] * invN - mu * mu;
    float s = g1[tid] * rsqrtf(var + 1e-5f);
    sfold[tid] = s;
    bfold[tid] = bb1[tid] - mu * s;
}

// --- fold BN1 into W1/bias, parallel: block = output row o in [0, 256) -----
// (W1 is 2D x D = 256 x 128: MUST be 256 blocks — round-5 bug was 128.)
__global__ __launch_bounds__(128) void k_fold1b(
    const float* __restrict__ sfold, const float* __restrict__ bfold,
    const float* __restrict__ W1, const float* __restrict__ b1,
    f16* __restrict__ W1b, float* __restrict__ badj)
{
    const int o = blockIdx.x, i = threadIdx.x;
    float wv = W1[(size_t)o * 128 + i];
    __shared__ float red[128];
    red[i] = wv * bfold[i];
    const int nt = o >> 4, lanelow = o & 15;
    const int kb = i >> 5, quad = (i >> 3) & 3, j = i & 7;
    W1b[(size_t)(((nt * 4 + kb) * 64 + lanelow + 16 * quad) * 8 + j)] = (f16)(wv * sfold[i]);
    __syncthreads();
#pragma unroll
    for (int off = 64; off; off >>= 1) {
        if (i < off) red[i] += red[i + off];
        __syncthreads();
    }
    if (i == 0) badj[o] = b1[o] + red[0];
}

// --- FFN1: u = relu(t1b @ W1s^T + badj), f16 frag order (K=256 layout). ----
__global__ __launch_bounds__(256) void k_ffn1(
    const f16* __restrict__ t1b, const f16* __restrict__ W1b,
    const float* __restrict__ badj, f16* __restrict__ ub, int N)
{
    const int slab = blockIdx.x, ch = blockIdx.y;
    const int w = threadIdx.x >> 6, lane = threadIdx.x & 63;
    const f16* A = t1b + (size_t)slab * ND128;

    h8 bfr[2][4];
#pragma unroll
    for (int nt = 0; nt < 2; ++nt)
#pragma unroll
        for (int kb = 0; kb < 4; ++kb) {
            int ntg = ch * 8 + 2 * w + nt;
            bfr[nt][kb] = *(const h8*)(W1b + (size_t)((ntg * 4 + kb) * 64 + lane) * 8);
        }

    f4 acc[8][2];
    f4 zero = {0.f, 0.f, 0.f, 0.f};
#pragma unroll
    for (int m = 0; m < 8; ++m) { acc[m][0] = zero; acc[m][1] = zero; }
#pragma unroll
    for (int m = 0; m < 8; ++m) {
#pragma unroll
        for (int kb = 0; kb < 4; ++kb) {
            h8 a = *(const h8*)(A + (size_t)((kb * 8 + m) * 64 + lane) * 8);
            acc[m][0] = __builtin_amdgcn_mfma_f32_16x16x32_f16(a, bfr[0][kb], acc[m][0], 0, 0, 0);
            acc[m][1] = __builtin_amdgcn_mfma_f32_16x16x32_f16(a, bfr[1][kb], acc[m][1], 0, 0, 0);
        }
    }

    const int c = lane & 15, quad = lane >> 4;
    const int kbu = ch * 4 + w;
#pragma unroll
    for (int m = 0; m < 8; ++m)
#pragma unroll
        for (int nt = 0; nt < 2; ++nt) {
            int colg = ch * 128 + w * 32 + nt * 16 + c;
            float ba = badj[colg];
            int quad2 = nt * 2 + (c >> 3), j = c & 7;
#pragma unroll
            for (int r = 0; r < 4; ++r) {
                int gr = slab * 128 + m * 16 + quad * 4 + r;
                if (gr < N) {
                    float v = fmaxf(acc[m][nt][r] + ba, 0.f);
                    ub[(size_t)slab * 32768 +
                       (size_t)(((kbu * 8 + m) * 64 + quad * 4 + r + 16 * quad2) * 8 + j)] = (f16)v;
                }
            }
        }
}

// --- FFN2: t2 = (s1*t1 + b1v + b2) + u @ W2^T, in place; BN2 sums. ---------
__global__ __launch_bounds__(256) void k_ffn2(
    const f16* __restrict__ ub, const f16* __restrict__ W2b,
    const float* __restrict__ sfold, const float* __restrict__ bfold,
    const float* __restrict__ b2, float* __restrict__ out,
    float* __restrict__ bn, int N)
{
    __shared__ float csum[128], csq[128], sS[128], sB[128];
    const int tid = threadIdx.x, slab = blockIdx.x;
    const int w = tid >> 6, lane = tid & 63;
    if (tid < 128) {
        csum[tid] = 0.f; csq[tid] = 0.f;
        sS[tid] = sfold[tid]; sB[tid] = bfold[tid] + b2[tid];
    }
    __syncthreads();
    const f16* A = ub + (size_t)slab * 32768;

    h8 bfr[2][8];
#pragma unroll
    for (int nt = 0; nt < 2; ++nt)
#pragma unroll
        for (int kb = 0; kb < 8; ++kb)
            bfr[nt][kb] = *(const h8*)(W2b + (size_t)(((2 * w + nt) * 8 + kb) * 64 + lane) * 8);

    f4 acc[8][2];
    f4 zero = {0.f, 0.f, 0.f, 0.f};
#pragma unroll
    for (int m = 0; m < 8; ++m) { acc[m][0] = zero; acc[m][1] = zero; }
#pragma unroll
    for (int m = 0; m < 8; ++m) {
#pragma unroll
        for (int kb = 0; kb < 8; ++kb) {
            h8 a = *(const h8*)(A + (size_t)((kb * 8 + m) * 64 + lane) * 8);
            acc[m][0] = __builtin_amdgcn_mfma_f32_16x16x32_f16(a, bfr[0][kb], acc[m][0], 0, 0, 0);
            acc[m][1] = __builtin_amdgcn_mfma_f32_16x16x32_f16(a, bfr[1][kb], acc[m][1], 0, 0, 0);
        }
    }

    const int c = lane & 15, quad = lane >> 4;
    float pcs[2] = {0.f, 0.f}, pcq[2] = {0.f, 0.f};
#pragma unroll
    for (int m = 0; m < 8; ++m)
#pragma unroll
        for (int nt = 0; nt < 2; ++nt) {
            int cl = w * 32 + nt * 16 + c;
            float ss = sS[cl], sb = sB[cl];
#pragma unroll
            for (int r = 0; r < 4; ++r) {
                int gr = slab * 128 + m * 16 + quad * 4 + r;
                if (gr < N) {
                    size_t gi = (size_t)gr * 128 + cl;
                    float v = acc[m][nt][r] + fmaf(ss, out[gi], sb);
                    out[gi] = v;
                    pcs[nt] += v; pcq[nt] += v * v;
                }
            }
        }
#pragma unroll
    for (int nt = 0; nt < 2; ++nt) {
        atomicAdd(&csum[w * 32 + nt * 16 + c], pcs[nt]);
        atomicAdd(&csq[w * 32 + nt * 16 + c], pcq[nt]);
    }
    __syncthreads();
    if (tid < 128) {
        atomicAdd(bn + 256 + tid, csum[tid]);
        atomicAdd(bn + 384 + tid, csq[tid]);
    }
}

// --- BN2 normalize in place ------------------------------------------------
__global__ __launch_bounds__(256) void k_bn2(
    float* __restrict__ out, const float* __restrict__ bn,
    const float* __restrict__ g2, const float* __restrict__ bb2, int N)
{
    __shared__ float sS[128], sB[128];
    const int tid = threadIdx.x;
    if (tid < 128) {
        float invN = 1.f / (float)N;
        float mu = bn[256 + tid] * invN;
        float var = bn[384 + tid] * invN - mu * mu;
        float scl = g2[tid] * rsqrtf(var + 1e-5f);
        sS[tid] = scl;
        sB[tid] = bb2[tid] - mu * scl;
    }
    __syncthreads();
    size_t idx = (size_t)blockIdx.x * 256 + tid;
    size_t total = (size_t)N * 32;
    if (idx < total) {
        int c0 = (int)((idx * 4) & 127);
        float4 v = *(const float4*)(out + idx * 4);
        v.x = fmaf(v.x, sS[c0 + 0], sB[c0 + 0]);
        v.y = fmaf(v.y, sS[c0 + 1], sB[c0 + 1]);
        v.z = fmaf(v.z, sS[c0 + 2], sB[c0 + 2]);
        v.w = fmaf(v.w, sS[c0 + 3], sB[c0 + 3]);
        *(float4*)(out + idx * 4) = v;
    }
}

extern "C" void kernel_launch(void* const* d_in, const int* in_sizes, int n_in,
                              void* d_out, int out_size, void* d_ws, size_t ws_size,
                              hipStream_t stream)
{
    const float* h   = (const float*)d_in[0];
    const int*   src = (const int*)d_in[1];
    const int*   dst = (const int*)d_in[2];
    const float* WQ  = (const float*)d_in[3];
    const float* WK  = (const float*)d_in[4];
    const float* WV  = (const float*)d_in[5];
    const float* WO  = (const float*)d_in[6];
    const float* bO  = (const float*)d_in[7];
    const float* W1  = (const float*)d_in[8];
    const float* b1  = (const float*)d_in[9];
    const float* W2  = (const float*)d_in[10];
    const float* b2  = (const float*)d_in[11];
    const float* g1  = (const float*)d_in[12];
    const float* bb1 = (const float*)d_in[13];
    const float* g2  = (const float*)d_in[14];
    const float* bb2 = (const float*)d_in[15];
    float* out = (float*)d_out;

    int N = in_sizes[0] / 128;
    int E = in_sizes[1];
    const int slabs = (N + 127) / 128;
    const size_t B1 = (size_t)slabs * 32768;   // bytes of one f16 N_pad x 128 buffer

    char* Wp = (char*)d_ws;
    f16* hb  = (f16*)Wp;                             // -> attnf after qkv
    f16* Qb  = (f16*)(Wp + B1);
    f16* Kb  = (f16*)(Wp + 2 * B1);
    f16* Vb  = (f16*)(Wp + 3 * B1);
    f16* t1b = (f16*)(Wp + 3 * B1);                  // overlays Vb (dead after attn)
    f16* ub  = (f16*)(Wp + B1);                      // overlays Qb+Kb (dead after attn)
    const size_t base = 4 * B1;
    f16* Wqb = (f16*)(Wp + base);
    f16* Wkb = (f16*)(Wp + base + 32768);
    f16* Wvb = (f16*)(Wp + base + 65536);
    f16* Wob = (f16*)(Wp + base + 98304);
    f16* W1b = (f16*)(Wp + base + 131072);
    f16* W2b = (f16*)(Wp + base + 196608);
    float* badj  = (float*)(Wp + base + 262144);
    float* sfold = (float*)(Wp + base + 263168);
    float* bfold = (float*)(Wp + base + 263680);
    float* bn    = (float*)(Wp + base + 264192);     // 512 floats (zeroed in cast_w)
    int* cursor  = (int*)(Wp + base + 266240);       // N ints (zeroed in k_csr)
    int* rowptr  = (int*)(Wp + base + 266240 + (size_t)N * 4);
    int* csr     = (int*)(Wp + base + 266240 + (size_t)N * 8 + 8);
    int* bsum    = (int*)((char*)csr + (size_t)E * 4);
    int* boff    = bsum + 512;

    k_cast_h<<<slabs, 256, 0, stream>>>(h, hb, N);
    k_cast_w<<<6, 256, 0, stream>>>(WQ, WK, WV, WO, W2, Wqb, Wkb, Wvb, Wob, W2b, bn);
    k_qkv<<<dim3(slabs, 3), 256, 0, stream>>>(hb, Wqb, Wkb, Wvb, Qb, Kb, Vb, N);
    {
        const int* srcp = src; const int* dstp = dst;
        void* args[] = {(void*)&srcp, (void*)&dstp, (void*)&cursor, (void*)&rowptr,
                        (void*)&csr, (void*)&bsum, (void*)&boff, (void*)&N, (void*)&E};
        hipLaunchCooperativeKernel((void*)k_csr, dim3(512), dim3(256), args, 0, stream);
    }
    k_attn<<<(N + 3) / 4, 256, 0, stream>>>(Qb, Kb, Vb, rowptr, csr, hb, N);
    k_oproj<<<slabs, 256, 0, stream>>>(hb, Wob, h, bO, out, t1b, bn, N);
    k_fold1a<<<1, 128, 0, stream>>>(bn, g1, bb1, sfold, bfold, N);
    k_fold1b<<<256, 128, 0, stream>>>(sfold, bfold, W1, b1, W1b, badj);   // 256 rows!
    k_ffn1<<<dim3(slabs, 2), 256, 0, stream>>>(t1b, W1b, badj, ub, N);
    k_ffn2<<<slabs, 256, 0, stream>>>(ub, W2b, sfold, bfold, b2, out, bn, N);
    k_bn2<<<(int)(((size_t)N * 32 + 255) / 256), 256, 0, stream>>>(out, bn, g2, bb2, N);
}

// Round 7
// 366.972 us; speedup vs baseline: 1.7658x; 1.7658x over previous
//
#include <hip/hip_runtime.h>
#include <math.h>

// ---------------------------------------------------------------------------
// GraphTransformerLayer N=50000, E=640000, D=128, H=8, DH=16  (gfx950)
// Round 7: f16 MFMA pipeline (round 6) + round-4's separate-kernel CSR build.
// Cooperative grid.sync() CSR (round 6) cost ~60us/barrier x 5 -> reverted.
//
// Fragment order for an MxK slab (M=128, K=KB*32):
//   elem index = ((kb*8 + mtile)*64 + lane)*8 + j
//   row = mtile*16 + (lane&15),  col = kb*32 + (lane>>4)*8 + j
// MFMA 16x16x32 f16: A[m=lane&15][k=(lane>>4)*8+j]; C/D: col=lane&15,
// row=(lane>>4)*4+reg.
// ---------------------------------------------------------------------------

#define ND128 16384
typedef _Float16 f16;
typedef __attribute__((ext_vector_type(8))) _Float16 h8;
typedef __attribute__((ext_vector_type(2))) _Float16 h2;
typedef __attribute__((ext_vector_type(4))) float f4;

// --- cast h (fp32 row-major) -> hb (f16 fragment order, zero-padded rows) --
__global__ __launch_bounds__(256) void k_cast_h(
    const float* __restrict__ h, f16* __restrict__ hb, int N)
{
    const int slab = blockIdx.x;
    const int tid = threadIdx.x;
#pragma unroll
    for (int it = 0; it < 8; ++it) {
        int cid = it * 256 + tid;              // 0..2047
        int lane = cid & 63;
        int m = (cid >> 6) & 7;
        int kb = cid >> 9;
        int row = slab * 128 + m * 16 + (lane & 15);
        int col = kb * 32 + (lane >> 4) * 8;
        f16 o8[8];
        if (row < N) {
            const float* p = h + (size_t)row * 128 + col;
            float4 f0 = *(const float4*)p;
            float4 f1 = *(const float4*)(p + 4);
            o8[0] = (f16)f0.x; o8[1] = (f16)f0.y; o8[2] = (f16)f0.z; o8[3] = (f16)f0.w;
            o8[4] = (f16)f1.x; o8[5] = (f16)f1.y; o8[6] = (f16)f1.z; o8[7] = (f16)f1.w;
        } else {
#pragma unroll
            for (int j = 0; j < 8; ++j) o8[j] = (f16)0.f;
        }
        *(h8*)(hb + (size_t)slab * ND128 + (size_t)cid * 8) = *(const h8*)o8;
    }
}

// --- cast weights -> f16 fragment order; block 0 also zeroes bn. -----------
__global__ __launch_bounds__(256) void k_cast_w(
    const float* __restrict__ WQ, const float* __restrict__ WK,
    const float* __restrict__ WV, const float* __restrict__ WO,
    const float* __restrict__ W2,
    f16* __restrict__ Wqb, f16* __restrict__ Wkb,
    f16* __restrict__ Wvb, f16* __restrict__ Wob, f16* __restrict__ W2b,
    float* __restrict__ bn)
{
    const int b = blockIdx.x;
    if (b == 0) { bn[threadIdx.x] = 0.f; bn[threadIdx.x + 256] = 0.f; }
    const float* Wsrc; f16* dst; int K, base;
    if (b < 4) {
        Wsrc = b == 0 ? WQ : b == 1 ? WK : b == 2 ? WV : WO;
        dst  = b == 0 ? Wqb : b == 1 ? Wkb : b == 2 ? Wvb : Wob;
        K = 128; base = 0;
    } else {
        Wsrc = W2; dst = W2b; K = 256; base = (b - 4) * 2048;
    }
#pragma unroll
    for (int it = 0; it < 8; ++it) {
        int cid = base + it * 256 + threadIdx.x;
        int lane = cid & 63;
        int kb, nt;
        if (K == 128) { kb = (cid >> 6) & 3; nt = cid >> 8; }
        else          { kb = (cid >> 6) & 7; nt = cid >> 9; }
        int row = nt * 16 + (lane & 15);
        int col = kb * 32 + (lane >> 4) * 8;
        const float* p = Wsrc + (size_t)row * K + col;
        f16 o8[8];
#pragma unroll
        for (int j = 0; j < 8; ++j) o8[j] = (f16)p[j];
        *(h8*)(dst + (size_t)cid * 8) = *(const h8*)o8;
    }
}

// --- QKV: out = hb @ Wb^T, f16 row-major outputs.  grid (slabs, 3) ---------
__global__ __launch_bounds__(256) void k_qkv(
    const f16* __restrict__ hb, const f16* __restrict__ Wqb,
    const f16* __restrict__ Wkb, const f16* __restrict__ Wvb,
    f16* __restrict__ Qb, f16* __restrict__ Kb, f16* __restrict__ Vb, int N)
{
    const int slab = blockIdx.x;
    const int w = threadIdx.x >> 6, lane = threadIdx.x & 63;
    const f16* __restrict__ Wb = blockIdx.y == 0 ? Wqb : blockIdx.y == 1 ? Wkb : Wvb;
    f16* __restrict__ Ob = blockIdx.y == 0 ? Qb : blockIdx.y == 1 ? Kb : Vb;
    const f16* A = hb + (size_t)slab * ND128;

    h8 bfr[2][4];
#pragma unroll
    for (int nt = 0; nt < 2; ++nt)
#pragma unroll
        for (int kb = 0; kb < 4; ++kb)
            bfr[nt][kb] = *(const h8*)(Wb + (size_t)(((2 * w + nt) * 4 + kb) * 64 + lane) * 8);

    f4 acc[8][2];
    f4 zero = {0.f, 0.f, 0.f, 0.f};
#pragma unroll
    for (int m = 0; m < 8; ++m) { acc[m][0] = zero; acc[m][1] = zero; }

#pragma unroll
    for (int m = 0; m < 8; ++m) {
#pragma unroll
        for (int kb = 0; kb < 4; ++kb) {
            h8 a = *(const h8*)(A + (size_t)((kb * 8 + m) * 64 + lane) * 8);
            acc[m][0] = __builtin_amdgcn_mfma_f32_16x16x32_f16(a, bfr[0][kb], acc[m][0], 0, 0, 0);
            acc[m][1] = __builtin_amdgcn_mfma_f32_16x16x32_f16(a, bfr[1][kb], acc[m][1], 0, 0, 0);
        }
    }

    const int c = lane & 15, quad = lane >> 4;
#pragma unroll
    for (int m = 0; m < 8; ++m)
#pragma unroll
        for (int nt = 0; nt < 2; ++nt) {
            int col = w * 32 + nt * 16 + c;
#pragma unroll
            for (int r = 0; r < 4; ++r) {
                int gr = slab * 128 + m * 16 + quad * 4 + r;
                if (gr < N) Ob[(size_t)gr * 128 + col] = (f16)acc[m][nt][r];
            }
        }
}

// --- CSR build (separate kernels; cursor pre-zeroed via memset) ------------
__global__ __launch_bounds__(256) void k_hist(
    const int* __restrict__ dst, int* __restrict__ cursor, int E)
{
    int e = blockIdx.x * 256 + threadIdx.x;
    if (e < E) atomicAdd(&cursor[dst[e]], 1);
}

// Pass A: per-block totals (2048 elems/block) via wave-shuffle reduce.
__global__ __launch_bounds__(256) void k_scanA(
    const int* __restrict__ cnt, int* __restrict__ bsum, int N)
{
    const int t = threadIdx.x;
    int base = blockIdx.x * 2048 + t * 8;
    int s = 0;
#pragma unroll
    for (int j = 0; j < 8; ++j) {
        int idx = base + j;
        if (idx < N) s += cnt[idx];
    }
#pragma unroll
    for (int off = 32; off; off >>= 1) s += __shfl_down(s, off, 64);
    __shared__ int ws4[4];
    if ((t & 63) == 0) ws4[t >> 6] = s;
    __syncthreads();
    if (t == 0) bsum[blockIdx.x] = ws4[0] + ws4[1] + ws4[2] + ws4[3];
}

// Pass B: tiny sequential scan of block sums (nb ~ 25); writes rowptr[N].
__global__ void k_scanB(
    const int* __restrict__ bsum, int* __restrict__ boff,
    int* __restrict__ rowptrN, int nb)
{
    if (threadIdx.x == 0) {
        int run = 0;
        for (int i = 0; i < nb; ++i) { boff[i] = run; run += bsum[i]; }
        *rowptrN = run;
    }
}

// Pass C: block-local exclusive scan + block offset -> rowptr & cursor.
__global__ __launch_bounds__(256) void k_scanC(
    const int* __restrict__ cnt, const int* __restrict__ boff,
    int* __restrict__ rowptr, int* __restrict__ cursor, int N)
{
    const int t = threadIdx.x;
    int base = blockIdx.x * 2048 + t * 8;
    int loc[8];
    int s = 0;
#pragma unroll
    for (int j = 0; j < 8; ++j) {
        int idx = base + j;
        loc[j] = (idx < N) ? cnt[idx] : 0;
        s += loc[j];
    }
    __shared__ int part[256];
    part[t] = s;
    __syncthreads();
    for (int off = 1; off < 256; off <<= 1) {
        int v = (t >= off) ? part[t - off] : 0;
        __syncthreads();
        part[t] += v;
        __syncthreads();
    }
    int run = boff[blockIdx.x] + (t ? part[t - 1] : 0);
#pragma unroll
    for (int j = 0; j < 8; ++j) {
        int idx = base + j;
        if (idx < N) { rowptr[idx] = run; cursor[idx] = run; run += loc[j]; }
    }
}

__global__ __launch_bounds__(256) void k_scatter(
    const int* __restrict__ src, const int* __restrict__ dst,
    int* __restrict__ cursor, int* __restrict__ csr_src, int E)
{
    int e = blockIdx.x * 256 + threadIdx.x;
    if (e < E) {
        int pos = atomicAdd(&cursor[dst[e]], 1);
        csr_src[pos] = src[e];
    }
}

// --- attention: one wave per node, lane owns channels (2l, 2l+1). ----------
// f16: dot via v_dot2_f32_f16, accumulate via packed h2 fma.
__global__ __launch_bounds__(256) void k_attn(
    const f16* __restrict__ Qb, const f16* __restrict__ Kb,
    const f16* __restrict__ Vb,
    const int* __restrict__ rowptr, const int* __restrict__ csr_src,
    f16* __restrict__ attnf, int N)
{
    const int node = blockIdx.x * 4 + (threadIdx.x >> 6);
    const int lane = threadIdx.x & 63;
    if (node >= N) return;
    const int beg = rowptr[node], end = rowptr[node + 1];
    const h2 q2 = ((const h2*)(Qb + (size_t)node * 128))[lane];
    h2 acc2 = {(f16)0.f, (f16)0.f};
    float z = 0.f;
    int i = beg;
    for (; i + 1 < end; i += 2) {
        int s0 = csr_src[i], s1 = csr_src[i + 1];
        h2 k0 = ((const h2*)(Kb + (size_t)s0 * 128))[lane];
        h2 v0 = ((const h2*)(Vb + (size_t)s0 * 128))[lane];
        h2 k1 = ((const h2*)(Kb + (size_t)s1 * 128))[lane];
        h2 v1 = ((const h2*)(Vb + (size_t)s1 * 128))[lane];
#if __has_builtin(__builtin_amdgcn_fdot2)
        float p0 = __builtin_amdgcn_fdot2(q2, k0, 0.f, false);
        float p1 = __builtin_amdgcn_fdot2(q2, k1, 0.f, false);
#else
        float p0 = (float)q2.x * (float)k0.x + (float)q2.y * (float)k0.y;
        float p1 = (float)q2.x * (float)k1.x + (float)q2.y * (float)k1.y;
#endif
        p0 += __shfl_xor(p0, 4, 8); p0 += __shfl_xor(p0, 2, 8); p0 += __shfl_xor(p0, 1, 8);
        p1 += __shfl_xor(p1, 4, 8); p1 += __shfl_xor(p1, 2, 8); p1 += __shfl_xor(p1, 1, 8);
        float sc0 = __expf(fminf(fmaxf(p0 * 0.25f, -5.f), 5.f));
        float sc1 = __expf(fminf(fmaxf(p1 * 0.25f, -5.f), 5.f));
        h2 s2a = {(f16)sc0, (f16)sc0};
        h2 s2b = {(f16)sc1, (f16)sc1};
        acc2 = v0 * s2a + acc2;
        acc2 = v1 * s2b + acc2;
        z += sc0 + sc1;
    }
    if (i < end) {
        int s0 = csr_src[i];
        h2 k0 = ((const h2*)(Kb + (size_t)s0 * 128))[lane];
        h2 v0 = ((const h2*)(Vb + (size_t)s0 * 128))[lane];
#if __has_builtin(__builtin_amdgcn_fdot2)
        float p0 = __builtin_amdgcn_fdot2(q2, k0, 0.f, false);
#else
        float p0 = (float)q2.x * (float)k0.x + (float)q2.y * (float)k0.y;
#endif
        p0 += __shfl_xor(p0, 4, 8); p0 += __shfl_xor(p0, 2, 8); p0 += __shfl_xor(p0, 1, 8);
        float sc0 = __expf(fminf(fmaxf(p0 * 0.25f, -5.f), 5.f));
        h2 s2a = {(f16)sc0, (f16)sc0};
        acc2 = v0 * s2a + acc2;
        z += sc0;
    }
    float inv = 1.f / z;
    h2 o2 = {(f16)((float)acc2.x * inv), (f16)((float)acc2.y * inv)};
    int slab = node >> 7, m = (node >> 4) & 7, lr = node & 15;
    int kb = lane >> 4, quad2 = (lane & 15) >> 2, j = (lane & 3) * 2;
    *(h2*)(attnf + (size_t)slab * ND128 +
           (size_t)(((kb * 8 + m) * 64 + lr + 16 * quad2) * 8 + j)) = o2;
}

// --- O-proj: t1 = attn @ WO^T + h + bO. fp32 out + f16 frag t1b + BN1 sums.
__global__ __launch_bounds__(256) void k_oproj(
    const f16* __restrict__ attnf, const f16* __restrict__ Wob,
    const float* __restrict__ h, const float* __restrict__ bO,
    float* __restrict__ out, f16* __restrict__ t1b,
    float* __restrict__ bn, int N)
{
    __shared__ float csum[128], csq[128];
    const int tid = threadIdx.x, slab = blockIdx.x;
    const int w = tid >> 6, lane = tid & 63;
    if (tid < 128) { csum[tid] = 0.f; csq[tid] = 0.f; }
    __syncthreads();
    const f16* A = attnf + (size_t)slab * ND128;

    h8 bfr[2][4];
#pragma unroll
    for (int nt = 0; nt < 2; ++nt)
#pragma unroll
        for (int kb = 0; kb < 4; ++kb)
            bfr[nt][kb] = *(const h8*)(Wob + (size_t)(((2 * w + nt) * 4 + kb) * 64 + lane) * 8);

    f4 acc[8][2];
    f4 zero = {0.f, 0.f, 0.f, 0.f};
#pragma unroll
    for (int m = 0; m < 8; ++m) { acc[m][0] = zero; acc[m][1] = zero; }
#pragma unroll
    for (int m = 0; m < 8; ++m) {
#pragma unroll
        for (int kb = 0; kb < 4; ++kb) {
            h8 a = *(const h8*)(A + (size_t)((kb * 8 + m) * 64 + lane) * 8);
            acc[m][0] = __builtin_amdgcn_mfma_f32_16x16x32_f16(a, bfr[0][kb], acc[m][0], 0, 0, 0);
            acc[m][1] = __builtin_amdgcn_mfma_f32_16x16x32_f16(a, bfr[1][kb], acc[m][1], 0, 0, 0);
        }
    }

    const int c = lane & 15, quad = lane >> 4;
    float pcs[2] = {0.f, 0.f}, pcq[2] = {0.f, 0.f};
#pragma unroll
    for (int m = 0; m < 8; ++m)
#pragma unroll
        for (int nt = 0; nt < 2; ++nt) {
            int cl = w * 32 + nt * 16 + c;
            float bo = bO[cl];
            int quad2 = nt * 2 + (c >> 3), j = c & 7;
#pragma unroll
            for (int r = 0; r < 4; ++r) {
                int rl = m * 16 + quad * 4 + r;
                int gr = slab * 128 + rl;
                if (gr < N) {
                    float v = acc[m][nt][r] + h[(size_t)gr * 128 + cl] + bo;
                    out[(size_t)gr * 128 + cl] = v;
                    t1b[(size_t)slab * ND128 +
                        (size_t)(((w * 8 + m) * 64 + quad * 4 + r + 16 * quad2) * 8 + j)] = (f16)v;
                    pcs[nt] += v; pcq[nt] += v * v;
                }
            }
        }
#pragma unroll
    for (int nt = 0; nt < 2; ++nt) {
        atomicAdd(&csum[w * 32 + nt * 16 + c], pcs[nt]);
        atomicAdd(&csq[w * 32 + nt * 16 + c], pcq[nt]);
    }
    __syncthreads();
    if (tid < 128) {
        atomicAdd(bn + tid, csum[tid]);
        atomicAdd(bn + 128 + tid, csq[tid]);
    }
}

// --- BN1 stats -> sfold/bfold (1 block, 128 threads) -----------------------
__global__ __launch_bounds__(128) void k_fold1a(
    const float* __restrict__ bn, const float* __restrict__ g1,
    const float* __restrict__ bb1,
    float* __restrict__ sfold, float* __restrict__ bfold, int N)
{
    const int tid = threadIdx.x;
    float invN = 1.f / (float)N;
    float mu = bn[tid] * invN;
    float var = bn[128 + tid] * invN - mu * mu;
    float s = g1[tid] * rsqrtf(var + 1e-5f);
    sfold[tid] = s;
    bfold[tid] = bb1[tid] - mu * s;
}

// --- fold BN1 into W1/bias, parallel: block = output row o in [0, 256) -----
__global__ __launch_bounds__(128) void k_fold1b(
    const float* __restrict__ sfold, const float* __restrict__ bfold,
    const float* __restrict__ W1, const float* __restrict__ b1,
    f16* __restrict__ W1b, float* __restrict__ badj)
{
    const int o = blockIdx.x, i = threadIdx.x;
    float wv = W1[(size_t)o * 128 + i];
    __shared__ float red[128];
    red[i] = wv * bfold[i];
    const int nt = o >> 4, lanelow = o & 15;
    const int kb = i >> 5, quad = (i >> 3) & 3, j = i & 7;
    W1b[(size_t)(((nt * 4 + kb) * 64 + lanelow + 16 * quad) * 8 + j)] = (f16)(wv * sfold[i]);
    __syncthreads();
#pragma unroll
    for (int off = 64; off; off >>= 1) {
        if (i < off) red[i] += red[i + off];
        __syncthreads();
    }
    if (i == 0) badj[o] = b1[o] + red[0];
}

// --- FFN1: u = relu(t1b @ W1s^T + badj), f16 frag order (K=256 layout). ----
__global__ __launch_bounds__(256) void k_ffn1(
    const f16* __restrict__ t1b, const f16* __restrict__ W1b,
    const float* __restrict__ badj, f16* __restrict__ ub, int N)
{
    const int slab = blockIdx.x, ch = blockIdx.y;
    const int w = threadIdx.x >> 6, lane = threadIdx.x & 63;
    const f16* A = t1b + (size_t)slab * ND128;

    h8 bfr[2][4];
#pragma unroll
    for (int nt = 0; nt < 2; ++nt)
#pragma unroll
        for (int kb = 0; kb < 4; ++kb) {
            int ntg = ch * 8 + 2 * w + nt;
            bfr[nt][kb] = *(const h8*)(W1b + (size_t)((ntg * 4 + kb) * 64 + lane) * 8);
        }

    f4 acc[8][2];
    f4 zero = {0.f, 0.f, 0.f, 0.f};
#pragma unroll
    for (int m = 0; m < 8; ++m) { acc[m][0] = zero; acc[m][1] = zero; }
#pragma unroll
    for (int m = 0; m < 8; ++m) {
#pragma unroll
        for (int kb = 0; kb < 4; ++kb) {
            h8 a = *(const h8*)(A + (size_t)((kb * 8 + m) * 64 + lane) * 8);
            acc[m][0] = __builtin_amdgcn_mfma_f32_16x16x32_f16(a, bfr[0][kb], acc[m][0], 0, 0, 0);
            acc[m][1] = __builtin_amdgcn_mfma_f32_16x16x32_f16(a, bfr[1][kb], acc[m][1], 0, 0, 0);
        }
    }

    const int c = lane & 15, quad = lane >> 4;
    const int kbu = ch * 4 + w;
#pragma unroll
    for (int m = 0; m < 8; ++m)
#pragma unroll
        for (int nt = 0; nt < 2; ++nt) {
            int colg = ch * 128 + w * 32 + nt * 16 + c;
            float ba = badj[colg];
            int quad2 = nt * 2 + (c >> 3), j = c & 7;
#pragma unroll
            for (int r = 0; r < 4; ++r) {
                int gr = slab * 128 + m * 16 + quad * 4 + r;
                if (gr < N) {
                    float v = fmaxf(acc[m][nt][r] + ba, 0.f);
                    ub[(size_t)slab * 32768 +
                       (size_t)(((kbu * 8 + m) * 64 + quad * 4 + r + 16 * quad2) * 8 + j)] = (f16)v;
                }
            }
        }
}

// --- FFN2: t2 = (s1*t1 + b1v + b2) + u @ W2^T, in place; BN2 sums. ---------
__global__ __launch_bounds__(256) void k_ffn2(
    const f16* __restrict__ ub, const f16* __restrict__ W2b,
    const float* __restrict__ sfold, const float* __restrict__ bfold,
    const float* __restrict__ b2, float* __restrict__ out,
    float* __restrict__ bn, int N)
{
    __shared__ float csum[128], csq[128], sS[128], sB[128];
    const int tid = threadIdx.x, slab = blockIdx.x;
    const int w = tid >> 6, lane = tid & 63;
    if (tid < 128) {
        csum[tid] = 0.f; csq[tid] = 0.f;
        sS[tid] = sfold[tid]; sB[tid] = bfold[tid] + b2[tid];
    }
    __syncthreads();
    const f16* A = ub + (size_t)slab * 32768;

    h8 bfr[2][8];
#pragma unroll
    for (int nt = 0; nt < 2; ++nt)
#pragma unroll
        for (int kb = 0; kb < 8; ++kb)
            bfr[nt][kb] = *(const h8*)(W2b + (size_t)(((2 * w + nt) * 8 + kb) * 64 + lane) * 8);

    f4 acc[8][2];
    f4 zero = {0.f, 0.f, 0.f, 0.f};
#pragma unroll
    for (int m = 0; m < 8; ++m) { acc[m][0] = zero; acc[m][1] = zero; }
#pragma unroll
    for (int m = 0; m < 8; ++m) {
#pragma unroll
        for (int kb = 0; kb < 8; ++kb) {
            h8 a = *(const h8*)(A + (size_t)((kb * 8 + m) * 64 + lane) * 8);
            acc[m][0] = __builtin_amdgcn_mfma_f32_16x16x32_f16(a, bfr[0][kb], acc[m][0], 0, 0, 0);
            acc[m][1] = __builtin_amdgcn_mfma_f32_16x16x32_f16(a, bfr[1][kb], acc[m][1], 0, 0, 0);
        }
    }

    const int c = lane & 15, quad = lane >> 4;
    float pcs[2] = {0.f, 0.f}, pcq[2] = {0.f, 0.f};
#pragma unroll
    for (int m = 0; m < 8; ++m)
#pragma unroll
        for (int nt = 0; nt < 2; ++nt) {
            int cl = w * 32 + nt * 16 + c;
            float ss = sS[cl], sb = sB[cl];
#pragma unroll
            for (int r = 0; r < 4; ++r) {
                int gr = slab * 128 + m * 16 + quad * 4 + r;
                if (gr < N) {
                    size_t gi = (size_t)gr * 128 + cl;
                    float v = acc[m][nt][r] + fmaf(ss, out[gi], sb);
                    out[gi] = v;
                    pcs[nt] += v; pcq[nt] += v * v;
                }
            }
        }
#pragma unroll
    for (int nt = 0; nt < 2; ++nt) {
        atomicAdd(&csum[w * 32 + nt * 16 + c], pcs[nt]);
        atomicAdd(&csq[w * 32 + nt * 16 + c], pcq[nt]);
    }
    __syncthreads();
    if (tid < 128) {
        atomicAdd(bn + 256 + tid, csum[tid]);
        atomicAdd(bn + 384 + tid, csq[tid]);
    }
}

// --- BN2 normalize in place ------------------------------------------------
__global__ __launch_bounds__(256) void k_bn2(
    float* __restrict__ out, const float* __restrict__ bn,
    const float* __restrict__ g2, const float* __restrict__ bb2, int N)
{
    __shared__ float sS[128], sB[128];
    const int tid = threadIdx.x;
    if (tid < 128) {
        float invN = 1.f / (float)N;
        float mu = bn[256 + tid] * invN;
        float var = bn[384 + tid] * invN - mu * mu;
        float scl = g2[tid] * rsqrtf(var + 1e-5f);
        sS[tid] = scl;
        sB[tid] = bb2[tid] - mu * scl;
    }
    __syncthreads();
    size_t idx = (size_t)blockIdx.x * 256 + tid;
    size_t total = (size_t)N * 32;
    if (idx < total) {
        int c0 = (int)((idx * 4) & 127);
        float4 v = *(const float4*)(out + idx * 4);
        v.x = fmaf(v.x, sS[c0 + 0], sB[c0 + 0]);
        v.y = fmaf(v.y, sS[c0 + 1], sB[c0 + 1]);
        v.z = fmaf(v.z, sS[c0 + 2], sB[c0 + 2]);
        v.w = fmaf(v.w, sS[c0 + 3], sB[c0 + 3]);
        *(float4*)(out + idx * 4) = v;
    }
}

extern "C" void kernel_launch(void* const* d_in, const int* in_sizes, int n_in,
                              void* d_out, int out_size, void* d_ws, size_t ws_size,
                              hipStream_t stream)
{
    const float* h   = (const float*)d_in[0];
    const int*   src = (const int*)d_in[1];
    const int*   dst = (const int*)d_in[2];
    const float* WQ  = (const float*)d_in[3];
    const float* WK  = (const float*)d_in[4];
    const float* WV  = (const float*)d_in[5];
    const float* WO  = (const float*)d_in[6];
    const float* bO  = (const float*)d_in[7];
    const float* W1  = (const float*)d_in[8];
    const float* b1  = (const float*)d_in[9];
    const float* W2  = (const float*)d_in[10];
    const float* b2  = (const float*)d_in[11];
    const float* g1  = (const float*)d_in[12];
    const float* bb1 = (const float*)d_in[13];
    const float* g2  = (const float*)d_in[14];
    const float* bb2 = (const float*)d_in[15];
    float* out = (float*)d_out;

    int N = in_sizes[0] / 128;
    int E = in_sizes[1];
    const int slabs = (N + 127) / 128;
    const int nsb = (N + 2047) / 2048;         // scan blocks (~25)
    const size_t B1 = (size_t)slabs * 32768;   // bytes of one f16 N_pad x 128 buffer

    char* Wp = (char*)d_ws;
    f16* hb  = (f16*)Wp;                             // -> attnf after qkv
    f16* Qb  = (f16*)(Wp + B1);
    f16* Kb  = (f16*)(Wp + 2 * B1);
    f16* Vb  = (f16*)(Wp + 3 * B1);
    f16* t1b = (f16*)(Wp + 3 * B1);                  // overlays Vb (dead after attn)
    f16* ub  = (f16*)(Wp + B1);                      // overlays Qb+Kb (dead after attn)
    const size_t base = 4 * B1;
    f16* Wqb = (f16*)(Wp + base);
    f16* Wkb = (f16*)(Wp + base + 32768);
    f16* Wvb = (f16*)(Wp + base + 65536);
    f16* Wob = (f16*)(Wp + base + 98304);
    f16* W1b = (f16*)(Wp + base + 131072);
    f16* W2b = (f16*)(Wp + base + 196608);
    float* badj  = (float*)(Wp + base + 262144);
    float* sfold = (float*)(Wp + base + 263168);
    float* bfold = (float*)(Wp + base + 263680);
    float* bn    = (float*)(Wp + base + 264192);     // 512 floats (zeroed in cast_w)
    int* cursor  = (int*)(Wp + base + 266240);       // N ints (zeroed via memset)
    int* rowptr  = (int*)(Wp + base + 266240 + (size_t)N * 4);
    int* csr     = (int*)(Wp + base + 266240 + (size_t)N * 8 + 8);
    int* bsum    = (int*)((char*)csr + (size_t)E * 4);
    int* boff    = bsum + 512;

    hipMemsetAsync(cursor, 0, (size_t)N * 4, stream);

    k_cast_h<<<slabs, 256, 0, stream>>>(h, hb, N);
    k_cast_w<<<6, 256, 0, stream>>>(WQ, WK, WV, WO, W2, Wqb, Wkb, Wvb, Wob, W2b, bn);
    k_qkv<<<dim3(slabs, 3), 256, 0, stream>>>(hb, Wqb, Wkb, Wvb, Qb, Kb, Vb, N);
    k_hist<<<(E + 255) / 256, 256, 0, stream>>>(dst, cursor, E);
    k_scanA<<<nsb, 256, 0, stream>>>(cursor, bsum, N);
    k_scanB<<<1, 64, 0, stream>>>(bsum, boff, rowptr + N, nsb);
    k_scanC<<<nsb, 256, 0, stream>>>(cursor, boff, rowptr, cursor, N);
    k_scatter<<<(E + 255) / 256, 256, 0, stream>>>(src, dst, cursor, csr, E);
    k_attn<<<(N + 3) / 4, 256, 0, stream>>>(Qb, Kb, Vb, rowptr, csr, hb, N);
    k_oproj<<<slabs, 256, 0, stream>>>(hb, Wob, h, bO, out, t1b, bn, N);
    k_fold1a<<<1, 128, 0, stream>>>(bn, g1, bb1, sfold, bfold, N);
    k_fold1b<<<256, 128, 0, stream>>>(sfold, bfold, W1, b1, W1b, badj);
    k_ffn1<<<dim3(slabs, 2), 256, 0, stream>>>(t1b, W1b, badj, ub, N);
    k_ffn2<<<slabs, 256, 0, stream>>>(ub, W2b, sfold, bfold, b2, out, bn, N);
    k_bn2<<<(int)(((size_t)N * 32 + 255) / 256), 256, 0, stream>>>(out, bn, g2, bb2, N);
}

// Round 8
// 348.714 us; speedup vs baseline: 1.8582x; 1.0524x over previous
//
#include <hip/hip_runtime.h>
#include <math.h>

// ---------------------------------------------------------------------------
// GraphTransformerLayer N=50000, E=640000, D=128, H=8, DH=16  (gfx950)
// Round 8: round-7 f16 MFMA pipeline with:
//   - k_attn unroll-4 (8 gathers in flight, 2 acc chains) -- latency-bound fix
//   - 12 launches (prep fusion; scanB folded into scanC; fold1a into fold1)
//   - t1 kept f16-only (oproj no fp32 write; ffn2 residual from t1b)
//
// Fragment order for an MxK slab (M=128, K=KB*32):
//   elem index = ((kb*8 + mtile)*64 + lane)*8 + j
//   row = mtile*16 + (lane&15),  col = kb*32 + (lane>>4)*8 + j
// MFMA 16x16x32 f16: A[m=lane&15][k=(lane>>4)*8+j]; C/D: col=lane&15,
// row=(lane>>4)*4+reg.
// ---------------------------------------------------------------------------

#define ND128 16384
typedef _Float16 f16;
typedef __attribute__((ext_vector_type(8))) _Float16 h8;
typedef __attribute__((ext_vector_type(2))) _Float16 h2;
typedef __attribute__((ext_vector_type(4))) float f4;

// --- prep: cast h -> hb (frag order); blocks 0-5 also cast weights;
// block 6 zeroes bn; every block zeroes its 128-int slice of cursor. --------
__global__ __launch_bounds__(256) void k_prep(
    const float* __restrict__ h, f16* __restrict__ hb,
    const float* __restrict__ WQ, const float* __restrict__ WK,
    const float* __restrict__ WV, const float* __restrict__ WO,
    const float* __restrict__ W2,
    f16* __restrict__ Wqb, f16* __restrict__ Wkb,
    f16* __restrict__ Wvb, f16* __restrict__ Wob, f16* __restrict__ W2b,
    float* __restrict__ bn, int* __restrict__ cursor, int N)
{
    const int slab = blockIdx.x;
    const int tid = threadIdx.x;
    // zero cursor slice
    if (tid < 128) {
        int ci = slab * 128 + tid;
        if (ci < N) cursor[ci] = 0;
    }
    if (slab == 6) { bn[tid] = 0.f; bn[tid + 256] = 0.f; }
    // cast h slab
#pragma unroll
    for (int it = 0; it < 8; ++it) {
        int cid = it * 256 + tid;              // 0..2047
        int lane = cid & 63;
        int m = (cid >> 6) & 7;
        int kb = cid >> 9;
        int row = slab * 128 + m * 16 + (lane & 15);
        int col = kb * 32 + (lane >> 4) * 8;
        f16 o8[8];
        if (row < N) {
            const float* p = h + (size_t)row * 128 + col;
            float4 f0 = *(const float4*)p;
            float4 f1 = *(const float4*)(p + 4);
            o8[0] = (f16)f0.x; o8[1] = (f16)f0.y; o8[2] = (f16)f0.z; o8[3] = (f16)f0.w;
            o8[4] = (f16)f1.x; o8[5] = (f16)f1.y; o8[6] = (f16)f1.z; o8[7] = (f16)f1.w;
        } else {
#pragma unroll
            for (int j = 0; j < 8; ++j) o8[j] = (f16)0.f;
        }
        *(h8*)(hb + (size_t)slab * ND128 + (size_t)cid * 8) = *(const h8*)o8;
    }
    // cast weights (blocks 0..5)
    if (slab < 6) {
        const float* Wsrc; f16* dst; int K, base;
        if (slab < 4) {
            Wsrc = slab == 0 ? WQ : slab == 1 ? WK : slab == 2 ? WV : WO;
            dst  = slab == 0 ? Wqb : slab == 1 ? Wkb : slab == 2 ? Wvb : Wob;
            K = 128; base = 0;
        } else {
            Wsrc = W2; dst = W2b; K = 256; base = (slab - 4) * 2048;
        }
#pragma unroll
        for (int it = 0; it < 8; ++it) {
            int cid = base + it * 256 + tid;
            int lane = cid & 63;
            int kb, nt;
            if (K == 128) { kb = (cid >> 6) & 3; nt = cid >> 8; }
            else          { kb = (cid >> 6) & 7; nt = cid >> 9; }
            int row = nt * 16 + (lane & 15);
            int col = kb * 32 + (lane >> 4) * 8;
            const float* p = Wsrc + (size_t)row * K + col;
            f16 o8[8];
#pragma unroll
            for (int j = 0; j < 8; ++j) o8[j] = (f16)p[j];
            *(h8*)(dst + (size_t)cid * 8) = *(const h8*)o8;
        }
    }
}

// --- QKV: out = hb @ Wb^T, f16 row-major outputs.  grid (slabs, 3) ---------
__global__ __launch_bounds__(256) void k_qkv(
    const f16* __restrict__ hb, const f16* __restrict__ Wqb,
    const f16* __restrict__ Wkb, const f16* __restrict__ Wvb,
    f16* __restrict__ Qb, f16* __restrict__ Kb, f16* __restrict__ Vb, int N)
{
    const int slab = blockIdx.x;
    const int w = threadIdx.x >> 6, lane = threadIdx.x & 63;
    const f16* __restrict__ Wb = blockIdx.y == 0 ? Wqb : blockIdx.y == 1 ? Wkb : Wvb;
    f16* __restrict__ Ob = blockIdx.y == 0 ? Qb : blockIdx.y == 1 ? Kb : Vb;
    const f16* A = hb + (size_t)slab * ND128;

    h8 bfr[2][4];
#pragma unroll
    for (int nt = 0; nt < 2; ++nt)
#pragma unroll
        for (int kb = 0; kb < 4; ++kb)
            bfr[nt][kb] = *(const h8*)(Wb + (size_t)(((2 * w + nt) * 4 + kb) * 64 + lane) * 8);

    f4 acc[8][2];
    f4 zero = {0.f, 0.f, 0.f, 0.f};
#pragma unroll
    for (int m = 0; m < 8; ++m) { acc[m][0] = zero; acc[m][1] = zero; }

#pragma unroll
    for (int m = 0; m < 8; ++m) {
#pragma unroll
        for (int kb = 0; kb < 4; ++kb) {
            h8 a = *(const h8*)(A + (size_t)((kb * 8 + m) * 64 + lane) * 8);
            acc[m][0] = __builtin_amdgcn_mfma_f32_16x16x32_f16(a, bfr[0][kb], acc[m][0], 0, 0, 0);
            acc[m][1] = __builtin_amdgcn_mfma_f32_16x16x32_f16(a, bfr[1][kb], acc[m][1], 0, 0, 0);
        }
    }

    const int c = lane & 15, quad = lane >> 4;
#pragma unroll
    for (int m = 0; m < 8; ++m)
#pragma unroll
        for (int nt = 0; nt < 2; ++nt) {
            int col = w * 32 + nt * 16 + c;
#pragma unroll
            for (int r = 0; r < 4; ++r) {
                int gr = slab * 128 + m * 16 + quad * 4 + r;
                if (gr < N) Ob[(size_t)gr * 128 + col] = (f16)acc[m][nt][r];
            }
        }
}

// --- CSR build -------------------------------------------------------------
__global__ __launch_bounds__(256) void k_hist(
    const int* __restrict__ dst, int* __restrict__ cursor, int E)
{
    int e = blockIdx.x * 256 + threadIdx.x;
    if (e < E) atomicAdd(&cursor[dst[e]], 1);
}

// Pass A: per-block totals (2048 elems/block) via wave-shuffle reduce.
__global__ __launch_bounds__(256) void k_scanA(
    const int* __restrict__ cnt, int* __restrict__ bsum, int N)
{
    const int t = threadIdx.x;
    int base = blockIdx.x * 2048 + t * 8;
    int s = 0;
#pragma unroll
    for (int j = 0; j < 8; ++j) {
        int idx = base + j;
        if (idx < N) s += cnt[idx];
    }
#pragma unroll
    for (int off = 32; off; off >>= 1) s += __shfl_down(s, off, 64);
    __shared__ int ws4[4];
    if ((t & 63) == 0) ws4[t >> 6] = s;
    __syncthreads();
    if (t == 0) bsum[blockIdx.x] = ws4[0] + ws4[1] + ws4[2] + ws4[3];
}

// Pass C: block-local scan; block offset computed in-block from bsum (~25). -
__global__ __launch_bounds__(256) void k_scanC(
    const int* __restrict__ cnt, const int* __restrict__ bsum,
    int* __restrict__ rowptr, int* __restrict__ cursor, int N, int nsb)
{
    const int t = threadIdx.x, b = blockIdx.x;
    __shared__ int sboff;
    if (t == 0) {
        int r = 0;
        for (int i2 = 0; i2 < b; ++i2) r += bsum[i2];
        sboff = r;
    }
    if (t == 64 && b == nsb - 1) {
        int r = 0;
        for (int i2 = 0; i2 < nsb; ++i2) r += bsum[i2];
        rowptr[N] = r;
    }
    int base = b * 2048 + t * 8;
    int loc[8];
    int s = 0;
#pragma unroll
    for (int j = 0; j < 8; ++j) {
        int idx = base + j;
        loc[j] = (idx < N) ? cnt[idx] : 0;
        s += loc[j];
    }
    __shared__ int part[256];
    part[t] = s;
    __syncthreads();
    for (int off = 1; off < 256; off <<= 1) {
        int v = (t >= off) ? part[t - off] : 0;
        __syncthreads();
        part[t] += v;
        __syncthreads();
    }
    int run = sboff + (t ? part[t - 1] : 0);
#pragma unroll
    for (int j = 0; j < 8; ++j) {
        int idx = base + j;
        if (idx < N) { rowptr[idx] = run; cursor[idx] = run; run += loc[j]; }
    }
}

__global__ __launch_bounds__(256) void k_scatter(
    const int* __restrict__ src, const int* __restrict__ dst,
    int* __restrict__ cursor, int* __restrict__ csr_src, int E)
{
    int e = blockIdx.x * 256 + threadIdx.x;
    if (e < E) {
        int pos = atomicAdd(&cursor[dst[e]], 1);
        csr_src[pos] = src[e];
    }
}

// --- attention: one wave per node, lane owns channels (2l, 2l+1). ----------
// Unroll-4: 8 gathers in flight, 4 independent shfl/exp chains, 2 acc chains.
__global__ __launch_bounds__(256) void k_attn(
    const f16* __restrict__ Qb, const f16* __restrict__ Kb,
    const f16* __restrict__ Vb,
    const int* __restrict__ rowptr, const int* __restrict__ csr_src,
    f16* __restrict__ attnf, int N)
{
    const int node = blockIdx.x * 4 + (threadIdx.x >> 6);
    const int lane = threadIdx.x & 63;
    if (node >= N) return;
    const int beg = rowptr[node], end = rowptr[node + 1];
    const h2 q2 = ((const h2*)(Qb + (size_t)node * 128))[lane];
    h2 accA = {(f16)0.f, (f16)0.f};
    h2 accB = {(f16)0.f, (f16)0.f};
    float zA = 0.f, zB = 0.f;
    int i = beg;
    for (; i + 3 < end; i += 4) {
        int s0 = csr_src[i], s1 = csr_src[i + 1];
        int s2 = csr_src[i + 2], s3 = csr_src[i + 3];
        h2 k0 = ((const h2*)(Kb + (size_t)s0 * 128))[lane];
        h2 k1 = ((const h2*)(Kb + (size_t)s1 * 128))[lane];
        h2 k2 = ((const h2*)(Kb + (size_t)s2 * 128))[lane];
        h2 k3 = ((const h2*)(Kb + (size_t)s3 * 128))[lane];
        h2 v0 = ((const h2*)(Vb + (size_t)s0 * 128))[lane];
        h2 v1 = ((const h2*)(Vb + (size_t)s1 * 128))[lane];
        h2 v2 = ((const h2*)(Vb + (size_t)s2 * 128))[lane];
        h2 v3 = ((const h2*)(Vb + (size_t)s3 * 128))[lane];
        float p0 = __builtin_amdgcn_fdot2(q2, k0, 0.f, false);
        float p1 = __builtin_amdgcn_fdot2(q2, k1, 0.f, false);
        float p2 = __builtin_amdgcn_fdot2(q2, k2, 0.f, false);
        float p3 = __builtin_amdgcn_fdot2(q2, k3, 0.f, false);
        p0 += __shfl_xor(p0, 4, 8); p1 += __shfl_xor(p1, 4, 8);
        p2 += __shfl_xor(p2, 4, 8); p3 += __shfl_xor(p3, 4, 8);
        p0 += __shfl_xor(p0, 2, 8); p1 += __shfl_xor(p1, 2, 8);
        p2 += __shfl_xor(p2, 2, 8); p3 += __shfl_xor(p3, 2, 8);
        p0 += __shfl_xor(p0, 1, 8); p1 += __shfl_xor(p1, 1, 8);
        p2 += __shfl_xor(p2, 1, 8); p3 += __shfl_xor(p3, 1, 8);
        float sc0 = __expf(fminf(fmaxf(p0 * 0.25f, -5.f), 5.f));
        float sc1 = __expf(fminf(fmaxf(p1 * 0.25f, -5.f), 5.f));
        float sc2 = __expf(fminf(fmaxf(p2 * 0.25f, -5.f), 5.f));
        float sc3 = __expf(fminf(fmaxf(p3 * 0.25f, -5.f), 5.f));
        h2 h0 = {(f16)sc0, (f16)sc0}, h1v = {(f16)sc1, (f16)sc1};
        h2 h2v = {(f16)sc2, (f16)sc2}, h3 = {(f16)sc3, (f16)sc3};
        accA = v0 * h0 + accA;  accB = v1 * h1v + accB;
        accA = v2 * h2v + accA; accB = v3 * h3 + accB;
        zA += sc0 + sc2; zB += sc1 + sc3;
    }
    for (; i < end; ++i) {
        int s0 = csr_src[i];
        h2 k0 = ((const h2*)(Kb + (size_t)s0 * 128))[lane];
        h2 v0 = ((const h2*)(Vb + (size_t)s0 * 128))[lane];
        float p0 = __builtin_amdgcn_fdot2(q2, k0, 0.f, false);
        p0 += __shfl_xor(p0, 4, 8); p0 += __shfl_xor(p0, 2, 8); p0 += __shfl_xor(p0, 1, 8);
        float sc0 = __expf(fminf(fmaxf(p0 * 0.25f, -5.f), 5.f));
        h2 h0 = {(f16)sc0, (f16)sc0};
        accA = v0 * h0 + accA;
        zA += sc0;
    }
    h2 acc2 = accA + accB;
    float z = zA + zB;
    float inv = 1.f / z;
    h2 o2 = {(f16)((float)acc2.x * inv), (f16)((float)acc2.y * inv)};
    int slab = node >> 7, m = (node >> 4) & 7, lr = node & 15;
    int kb = lane >> 4, quad2 = (lane & 15) >> 2, j = (lane & 3) * 2;
    *(h2*)(attnf + (size_t)slab * ND128 +
           (size_t)(((kb * 8 + m) * 64 + lr + 16 * quad2) * 8 + j)) = o2;
}

// --- O-proj: t1 = attn @ WO^T + h + bO -> f16 frag t1b only; BN1 sums. -----
__global__ __launch_bounds__(256) void k_oproj(
    const f16* __restrict__ attnf, const f16* __restrict__ Wob,
    const float* __restrict__ h, const float* __restrict__ bO,
    f16* __restrict__ t1b, float* __restrict__ bn, int N)
{
    __shared__ float csum[128], csq[128];
    const int tid = threadIdx.x, slab = blockIdx.x;
    const int w = tid >> 6, lane = tid & 63;
    if (tid < 128) { csum[tid] = 0.f; csq[tid] = 0.f; }
    __syncthreads();
    const f16* A = attnf + (size_t)slab * ND128;

    h8 bfr[2][4];
#pragma unroll
    for (int nt = 0; nt < 2; ++nt)
#pragma unroll
        for (int kb = 0; kb < 4; ++kb)
            bfr[nt][kb] = *(const h8*)(Wob + (size_t)(((2 * w + nt) * 4 + kb) * 64 + lane) * 8);

    f4 acc[8][2];
    f4 zero = {0.f, 0.f, 0.f, 0.f};
#pragma unroll
    for (int m = 0; m < 8; ++m) { acc[m][0] = zero; acc[m][1] = zero; }
#pragma unroll
    for (int m = 0; m < 8; ++m) {
#pragma unroll
        for (int kb = 0; kb < 4; ++kb) {
            h8 a = *(const h8*)(A + (size_t)((kb * 8 + m) * 64 + lane) * 8);
            acc[m][0] = __builtin_amdgcn_mfma_f32_16x16x32_f16(a, bfr[0][kb], acc[m][0], 0, 0, 0);
            acc[m][1] = __builtin_amdgcn_mfma_f32_16x16x32_f16(a, bfr[1][kb], acc[m][1], 0, 0, 0);
        }
    }

    const int c = lane & 15, quad = lane >> 4;
    float pcs[2] = {0.f, 0.f}, pcq[2] = {0.f, 0.f};
#pragma unroll
    for (int m = 0; m < 8; ++m)
#pragma unroll
        for (int nt = 0; nt < 2; ++nt) {
            int cl = w * 32 + nt * 16 + c;
            float bo = bO[cl];
            int quad2 = nt * 2 + (c >> 3), j = c & 7;
#pragma unroll
            for (int r = 0; r < 4; ++r) {
                int rl = m * 16 + quad * 4 + r;
                int gr = slab * 128 + rl;
                if (gr < N) {
                    float v = acc[m][nt][r] + h[(size_t)gr * 128 + cl] + bo;
                    t1b[(size_t)slab * ND128 +
                        (size_t)(((w * 8 + m) * 64 + quad * 4 + r + 16 * quad2) * 8 + j)] = (f16)v;
                    pcs[nt] += v; pcq[nt] += v * v;
                }
            }
        }
#pragma unroll
    for (int nt = 0; nt < 2; ++nt) {
        atomicAdd(&csum[w * 32 + nt * 16 + c], pcs[nt]);
        atomicAdd(&csq[w * 32 + nt * 16 + c], pcq[nt]);
    }
    __syncthreads();
    if (tid < 128) {
        atomicAdd(bn + tid, csum[tid]);
        atomicAdd(bn + 128 + tid, csq[tid]);
    }
}

// --- fold BN1 into W1/bias. 256 blocks (one per W1 row); per-block stats
// recompute is 128 cheap loads. Block 0 also publishes sfold/bfold. ---------
__global__ __launch_bounds__(128) void k_fold1(
    const float* __restrict__ bn, const float* __restrict__ g1,
    const float* __restrict__ bb1, const float* __restrict__ W1,
    const float* __restrict__ b1, f16* __restrict__ W1b,
    float* __restrict__ badj, float* __restrict__ sfold,
    float* __restrict__ bfold, int N)
{
    const int o = blockIdx.x, i = threadIdx.x;
    float invN = 1.f / (float)N;
    float mu = bn[i] * invN;
    float var = bn[128 + i] * invN - mu * mu;
    float s = g1[i] * rsqrtf(var + 1e-5f);
    float bb = bb1[i] - mu * s;
    if (o == 0) { sfold[i] = s; bfold[i] = bb; }
    float wv = W1[(size_t)o * 128 + i];
    __shared__ float red[128];
    red[i] = wv * bb;
    const int nt = o >> 4, lanelow = o & 15;
    const int kb = i >> 5, quad = (i >> 3) & 3, j = i & 7;
    W1b[(size_t)(((nt * 4 + kb) * 64 + lanelow + 16 * quad) * 8 + j)] = (f16)(wv * s);
    __syncthreads();
#pragma unroll
    for (int off = 64; off; off >>= 1) {
        if (i < off) red[i] += red[i + off];
        __syncthreads();
    }
    if (i == 0) badj[o] = b1[o] + red[0];
}

// --- FFN1: u = relu(t1b @ W1s^T + badj), f16 frag order (K=256 layout). ----
__global__ __launch_bounds__(256) void k_ffn1(
    const f16* __restrict__ t1b, const f16* __restrict__ W1b,
    const float* __restrict__ badj, f16* __restrict__ ub, int N)
{
    const int slab = blockIdx.x, ch = blockIdx.y;
    const int w = threadIdx.x >> 6, lane = threadIdx.x & 63;
    const f16* A = t1b + (size_t)slab * ND128;

    h8 bfr[2][4];
#pragma unroll
    for (int nt = 0; nt < 2; ++nt)
#pragma unroll
        for (int kb = 0; kb < 4; ++kb) {
            int ntg = ch * 8 + 2 * w + nt;
            bfr[nt][kb] = *(const h8*)(W1b + (size_t)((ntg * 4 + kb) * 64 + lane) * 8);
        }

    f4 acc[8][2];
    f4 zero = {0.f, 0.f, 0.f, 0.f};
#pragma unroll
    for (int m = 0; m < 8; ++m) { acc[m][0] = zero; acc[m][1] = zero; }
#pragma unroll
    for (int m = 0; m < 8; ++m) {
#pragma unroll
        for (int kb = 0; kb < 4; ++kb) {
            h8 a = *(const h8*)(A + (size_t)((kb * 8 + m) * 64 + lane) * 8);
            acc[m][0] = __builtin_amdgcn_mfma_f32_16x16x32_f16(a, bfr[0][kb], acc[m][0], 0, 0, 0);
            acc[m][1] = __builtin_amdgcn_mfma_f32_16x16x32_f16(a, bfr[1][kb], acc[m][1], 0, 0, 0);
        }
    }

    const int c = lane & 15, quad = lane >> 4;
    const int kbu = ch * 4 + w;
#pragma unroll
    for (int m = 0; m < 8; ++m)
#pragma unroll
        for (int nt = 0; nt < 2; ++nt) {
            int colg = ch * 128 + w * 32 + nt * 16 + c;
            float ba = badj[colg];
            int quad2 = nt * 2 + (c >> 3), j = c & 7;
#pragma unroll
            for (int r = 0; r < 4; ++r) {
                int gr = slab * 128 + m * 16 + quad * 4 + r;
                if (gr < N) {
                    float v = fmaxf(acc[m][nt][r] + ba, 0.f);
                    ub[(size_t)slab * 32768 +
                       (size_t)(((kbu * 8 + m) * 64 + quad * 4 + r + 16 * quad2) * 8 + j)] = (f16)v;
                }
            }
        }
}

// --- FFN2: t2 = (s1*t1 + b1v + b2) + u @ W2^T; t1 residual from f16 t1b;
// writes fp32 out; BN2 sums. ------------------------------------------------
__global__ __launch_bounds__(256) void k_ffn2(
    const f16* __restrict__ ub, const f16* __restrict__ W2b,
    const f16* __restrict__ t1b,
    const float* __restrict__ sfold, const float* __restrict__ bfold,
    const float* __restrict__ b2, float* __restrict__ out,
    float* __restrict__ bn, int N)
{
    __shared__ float csum[128], csq[128], sS[128], sB[128];
    const int tid = threadIdx.x, slab = blockIdx.x;
    const int w = tid >> 6, lane = tid & 63;
    if (tid < 128) {
        csum[tid] = 0.f; csq[tid] = 0.f;
        sS[tid] = sfold[tid]; sB[tid] = bfold[tid] + b2[tid];
    }
    __syncthreads();
    const f16* A = ub + (size_t)slab * 32768;
    const f16* T1 = t1b + (size_t)slab * ND128;

    h8 bfr[2][8];
#pragma unroll
    for (int nt = 0; nt < 2; ++nt)
#pragma unroll
        for (int kb = 0; kb < 8; ++kb)
            bfr[nt][kb] = *(const h8*)(W2b + (size_t)(((2 * w + nt) * 8 + kb) * 64 + lane) * 8);

    f4 acc[8][2];
    f4 zero = {0.f, 0.f, 0.f, 0.f};
#pragma unroll
    for (int m = 0; m < 8; ++m) { acc[m][0] = zero; acc[m][1] = zero; }
#pragma unroll
    for (int m = 0; m < 8; ++m) {
#pragma unroll
        for (int kb = 0; kb < 8; ++kb) {
            h8 a = *(const h8*)(A + (size_t)((kb * 8 + m) * 64 + lane) * 8);
            acc[m][0] = __builtin_amdgcn_mfma_f32_16x16x32_f16(a, bfr[0][kb], acc[m][0], 0, 0, 0);
            acc[m][1] = __builtin_amdgcn_mfma_f32_16x16x32_f16(a, bfr[1][kb], acc[m][1], 0, 0, 0);
        }
    }

    const int c = lane & 15, quad = lane >> 4;
    float pcs[2] = {0.f, 0.f}, pcq[2] = {0.f, 0.f};
#pragma unroll
    for (int m = 0; m < 8; ++m)
#pragma unroll
        for (int nt = 0; nt < 2; ++nt) {
            int cl = w * 32 + nt * 16 + c;
            float ss = sS[cl], sb = sB[cl];
            int quad2 = nt * 2 + (c >> 3), j = c & 7;
#pragma unroll
            for (int r = 0; r < 4; ++r) {
                int gr = slab * 128 + m * 16 + quad * 4 + r;
                if (gr < N) {
                    float t1v = (float)T1[(size_t)(((w * 8 + m) * 64 + quad * 4 + r + 16 * quad2) * 8 + j)];
                    float v = acc[m][nt][r] + fmaf(ss, t1v, sb);
                    out[(size_t)gr * 128 + cl] = v;
                    pcs[nt] += v; pcq[nt] += v * v;
                }
            }
        }
#pragma unroll
    for (int nt = 0; nt < 2; ++nt) {
        atomicAdd(&csum[w * 32 + nt * 16 + c], pcs[nt]);
        atomicAdd(&csq[w * 32 + nt * 16 + c], pcq[nt]);
    }
    __syncthreads();
    if (tid < 128) {
        atomicAdd(bn + 256 + tid, csum[tid]);
        atomicAdd(bn + 384 + tid, csq[tid]);
    }
}

// --- BN2 normalize in place ------------------------------------------------
__global__ __launch_bounds__(256) void k_bn2(
    float* __restrict__ out, const float* __restrict__ bn,
    const float* __restrict__ g2, const float* __restrict__ bb2, int N)
{
    __shared__ float sS[128], sB[128];
    const int tid = threadIdx.x;
    if (tid < 128) {
        float invN = 1.f / (float)N;
        float mu = bn[256 + tid] * invN;
        float var = bn[384 + tid] * invN - mu * mu;
        float scl = g2[tid] * rsqrtf(var + 1e-5f);
        sS[tid] = scl;
        sB[tid] = bb2[tid] - mu * scl;
    }
    __syncthreads();
    size_t idx = (size_t)blockIdx.x * 256 + tid;
    size_t total = (size_t)N * 32;
    if (idx < total) {
        int c0 = (int)((idx * 4) & 127);
        float4 v = *(const float4*)(out + idx * 4);
        v.x = fmaf(v.x, sS[c0 + 0], sB[c0 + 0]);
        v.y = fmaf(v.y, sS[c0 + 1], sB[c0 + 1]);
        v.z = fmaf(v.z, sS[c0 + 2], sB[c0 + 2]);
        v.w = fmaf(v.w, sS[c0 + 3], sB[c0 + 3]);
        *(float4*)(out + idx * 4) = v;
    }
}

extern "C" void kernel_launch(void* const* d_in, const int* in_sizes, int n_in,
                              void* d_out, int out_size, void* d_ws, size_t ws_size,
                              hipStream_t stream)
{
    const float* h   = (const float*)d_in[0];
    const int*   src = (const int*)d_in[1];
    const int*   dst = (const int*)d_in[2];
    const float* WQ  = (const float*)d_in[3];
    const float* WK  = (const float*)d_in[4];
    const float* WV  = (const float*)d_in[5];
    const float* WO  = (const float*)d_in[6];
    const float* bO  = (const float*)d_in[7];
    const float* W1  = (const float*)d_in[8];
    const float* b1  = (const float*)d_in[9];
    const float* W2  = (const float*)d_in[10];
    const float* b2  = (const float*)d_in[11];
    const float* g1  = (const float*)d_in[12];
    const float* bb1 = (const float*)d_in[13];
    const float* g2  = (const float*)d_in[14];
    const float* bb2 = (const float*)d_in[15];
    float* out = (float*)d_out;

    int N = in_sizes[0] / 128;
    int E = in_sizes[1];
    const int slabs = (N + 127) / 128;
    const int nsb = (N + 2047) / 2048;         // scan blocks (~25)
    const size_t B1 = (size_t)slabs * 32768;   // bytes of one f16 N_pad x 128 buffer

    char* Wp = (char*)d_ws;
    f16* hb  = (f16*)Wp;                             // -> attnf after qkv
    f16* Qb  = (f16*)(Wp + B1);
    f16* Kb  = (f16*)(Wp + 2 * B1);
    f16* Vb  = (f16*)(Wp + 3 * B1);
    f16* t1b = (f16*)(Wp + 3 * B1);                  // overlays Vb (dead after attn)
    f16* ub  = (f16*)(Wp + B1);                      // overlays Qb+Kb (dead after attn)
    const size_t base = 4 * B1;
    f16* Wqb = (f16*)(Wp + base);
    f16* Wkb = (f16*)(Wp + base + 32768);
    f16* Wvb = (f16*)(Wp + base + 65536);
    f16* Wob = (f16*)(Wp + base + 98304);
    f16* W1b = (f16*)(Wp + base + 131072);
    f16* W2b = (f16*)(Wp + base + 196608);
    float* badj  = (float*)(Wp + base + 262144);
    float* sfold = (float*)(Wp + base + 263168);
    float* bfold = (float*)(Wp + base + 263680);
    float* bn    = (float*)(Wp + base + 264192);     // 512 floats (zeroed in prep)
    int* cursor  = (int*)(Wp + base + 266240);       // N ints (zeroed in prep)
    int* rowptr  = (int*)(Wp + base + 266240 + (size_t)N * 4);
    int* csr     = (int*)(Wp + base + 266240 + (size_t)N * 8 + 8);
    int* bsum    = (int*)((char*)csr + (size_t)E * 4);

    k_prep<<<slabs, 256, 0, stream>>>(h, hb, WQ, WK, WV, WO, W2,
                                      Wqb, Wkb, Wvb, Wob, W2b, bn, cursor, N);
    k_qkv<<<dim3(slabs, 3), 256, 0, stream>>>(hb, Wqb, Wkb, Wvb, Qb, Kb, Vb, N);
    k_hist<<<(E + 255) / 256, 256, 0, stream>>>(dst, cursor, E);
    k_scanA<<<nsb, 256, 0, stream>>>(cursor, bsum, N);
    k_scanC<<<nsb, 256, 0, stream>>>(cursor, bsum, rowptr, cursor, N, nsb);
    k_scatter<<<(E + 255) / 256, 256, 0, stream>>>(src, dst, cursor, csr, E);
    k_attn<<<(N + 3) / 4, 256, 0, stream>>>(Qb, Kb, Vb, rowptr, csr, hb, N);
    k_oproj<<<slabs, 256, 0, stream>>>(hb, Wob, h, bO, t1b, bn, N);
    k_fold1<<<256, 128, 0, stream>>>(bn, g1, bb1, W1, b1, W1b, badj, sfold, bfold, N);
    k_ffn1<<<dim3(slabs, 2), 256, 0, stream>>>(t1b, W1b, badj, ub, N);
    k_ffn2<<<slabs, 256, 0, stream>>>(ub, W2b, t1b, sfold, bfold, b2, out, bn, N);
    k_bn2<<<(int)(((size_t)N * 32 + 255) / 256), 256, 0, stream>>>(out, bn, g2, bb2, N);
}

// Round 9
// 331.884 us; speedup vs baseline: 1.9525x; 1.0507x over previous
//
#include <hip/hip_runtime.h>
#include <math.h>

// ---------------------------------------------------------------------------
// GraphTransformerLayer N=50000, E=640000, D=128, H=8, DH=16  (gfx950)
// Round 9: round-8 pipeline + operand-swapped MFMA in all GEMMs.
// mfma(Wfrag, hfrag) yields C^T lane layout: row = m*16+(lane&15) (fixed),
// cols = w*32+nt*16+quad*4+{0..3} (contiguous) -> 8B/16B vector stores in all
// epilogues, float4 residual/bias loads, h4 t1 loads. BN col-sums via
// width-16 shfl reduce + conflict-free LDS atomics.
//
// Fragment order for an MxK slab (M=128, K=KB*32):
//   elem index = ((kb*8 + mtile)*64 + lane)*8 + j
//   row = mtile*16 + (lane&15),  col = kb*32 + (lane>>4)*8 + j
// ---------------------------------------------------------------------------

#define ND128 16384
typedef _Float16 f16;
typedef __attribute__((ext_vector_type(8))) _Float16 h8;
typedef __attribute__((ext_vector_type(4))) _Float16 h4;
typedef __attribute__((ext_vector_type(2))) _Float16 h2;
typedef __attribute__((ext_vector_type(4))) float f4;

// --- prep: cast h -> hb (frag order); blocks 0-5 also cast weights;
// block 6 zeroes bn; every block zeroes its 128-int slice of cursor. --------
__global__ __launch_bounds__(256) void k_prep(
    const float* __restrict__ h, f16* __restrict__ hb,
    const float* __restrict__ WQ, const float* __restrict__ WK,
    const float* __restrict__ WV, const float* __restrict__ WO,
    const float* __restrict__ W2,
    f16* __restrict__ Wqb, f16* __restrict__ Wkb,
    f16* __restrict__ Wvb, f16* __restrict__ Wob, f16* __restrict__ W2b,
    float* __restrict__ bn, int* __restrict__ cursor, int N)
{
    const int slab = blockIdx.x;
    const int tid = threadIdx.x;
    if (tid < 128) {
        int ci = slab * 128 + tid;
        if (ci < N) cursor[ci] = 0;
    }
    if (slab == 6) { bn[tid] = 0.f; bn[tid + 256] = 0.f; }
#pragma unroll
    for (int it = 0; it < 8; ++it) {
        int cid = it * 256 + tid;              // 0..2047
        int lane = cid & 63;
        int m = (cid >> 6) & 7;
        int kb = cid >> 9;
        int row = slab * 128 + m * 16 + (lane & 15);
        int col = kb * 32 + (lane >> 4) * 8;
        f16 o8[8];
        if (row < N) {
            const float* p = h + (size_t)row * 128 + col;
            float4 f0 = *(const float4*)p;
            float4 f1 = *(const float4*)(p + 4);
            o8[0] = (f16)f0.x; o8[1] = (f16)f0.y; o8[2] = (f16)f0.z; o8[3] = (f16)f0.w;
            o8[4] = (f16)f1.x; o8[5] = (f16)f1.y; o8[6] = (f16)f1.z; o8[7] = (f16)f1.w;
        } else {
#pragma unroll
            for (int j = 0; j < 8; ++j) o8[j] = (f16)0.f;
        }
        *(h8*)(hb + (size_t)slab * ND128 + (size_t)cid * 8) = *(const h8*)o8;
    }
    if (slab < 6) {
        const float* Wsrc; f16* dst; int K, base;
        if (slab < 4) {
            Wsrc = slab == 0 ? WQ : slab == 1 ? WK : slab == 2 ? WV : WO;
            dst  = slab == 0 ? Wqb : slab == 1 ? Wkb : slab == 2 ? Wvb : Wob;
            K = 128; base = 0;
        } else {
            Wsrc = W2; dst = W2b; K = 256; base = (slab - 4) * 2048;
        }
#pragma unroll
        for (int it = 0; it < 8; ++it) {
            int cid = base + it * 256 + tid;
            int lane = cid & 63;
            int kb, nt;
            if (K == 128) { kb = (cid >> 6) & 3; nt = cid >> 8; }
            else          { kb = (cid >> 6) & 7; nt = cid >> 9; }
            int row = nt * 16 + (lane & 15);
            int col = kb * 32 + (lane >> 4) * 8;
            const float* p = Wsrc + (size_t)row * K + col;
            f16 o8[8];
#pragma unroll
            for (int j = 0; j < 8; ++j) o8[j] = (f16)p[j];
            *(h8*)(dst + (size_t)cid * 8) = *(const h8*)o8;
        }
    }
}

// --- QKV: out = hb @ Wb^T (swapped mfma -> row-contiguous stores). ---------
__global__ __launch_bounds__(256) void k_qkv(
    const f16* __restrict__ hb, const f16* __restrict__ Wqb,
    const f16* __restrict__ Wkb, const f16* __restrict__ Wvb,
    f16* __restrict__ Qb, f16* __restrict__ Kb, f16* __restrict__ Vb, int N)
{
    const int slab = blockIdx.x;
    const int w = threadIdx.x >> 6, lane = threadIdx.x & 63;
    const f16* __restrict__ Wb = blockIdx.y == 0 ? Wqb : blockIdx.y == 1 ? Wkb : Wvb;
    f16* __restrict__ Ob = blockIdx.y == 0 ? Qb : blockIdx.y == 1 ? Kb : Vb;
    const f16* A = hb + (size_t)slab * ND128;

    h8 bfr[2][4];
#pragma unroll
    for (int nt = 0; nt < 2; ++nt)
#pragma unroll
        for (int kb = 0; kb < 4; ++kb)
            bfr[nt][kb] = *(const h8*)(Wb + (size_t)(((2 * w + nt) * 4 + kb) * 64 + lane) * 8);

    f4 acc[8][2];
    f4 zero = {0.f, 0.f, 0.f, 0.f};
#pragma unroll
    for (int m = 0; m < 8; ++m) { acc[m][0] = zero; acc[m][1] = zero; }

#pragma unroll
    for (int m = 0; m < 8; ++m) {
#pragma unroll
        for (int kb = 0; kb < 4; ++kb) {
            h8 a = *(const h8*)(A + (size_t)((kb * 8 + m) * 64 + lane) * 8);
            acc[m][0] = __builtin_amdgcn_mfma_f32_16x16x32_f16(bfr[0][kb], a, acc[m][0], 0, 0, 0);
            acc[m][1] = __builtin_amdgcn_mfma_f32_16x16x32_f16(bfr[1][kb], a, acc[m][1], 0, 0, 0);
        }
    }

    const int rl = lane & 15, quad = lane >> 4;
#pragma unroll
    for (int m = 0; m < 8; ++m) {
        int gr = slab * 128 + m * 16 + rl;
        if (gr < N) {
#pragma unroll
            for (int nt = 0; nt < 2; ++nt) {
                h4 o;
                o[0] = (f16)acc[m][nt][0]; o[1] = (f16)acc[m][nt][1];
                o[2] = (f16)acc[m][nt][2]; o[3] = (f16)acc[m][nt][3];
                *(h4*)(Ob + (size_t)gr * 128 + w * 32 + nt * 16 + quad * 4) = o;
            }
        }
    }
}

// --- CSR build -------------------------------------------------------------
__global__ __launch_bounds__(256) void k_hist(
    const int* __restrict__ dst, int* __restrict__ cursor, int E)
{
    int e = blockIdx.x * 256 + threadIdx.x;
    if (e < E) atomicAdd(&cursor[dst[e]], 1);
}

__global__ __launch_bounds__(256) void k_scanA(
    const int* __restrict__ cnt, int* __restrict__ bsum, int N)
{
    const int t = threadIdx.x;
    int base = blockIdx.x * 2048 + t * 8;
    int s = 0;
#pragma unroll
    for (int j = 0; j < 8; ++j) {
        int idx = base + j;
        if (idx < N) s += cnt[idx];
    }
#pragma unroll
    for (int off = 32; off; off >>= 1) s += __shfl_down(s, off, 64);
    __shared__ int ws4[4];
    if ((t & 63) == 0) ws4[t >> 6] = s;
    __syncthreads();
    if (t == 0) bsum[blockIdx.x] = ws4[0] + ws4[1] + ws4[2] + ws4[3];
}

__global__ __launch_bounds__(256) void k_scanC(
    const int* __restrict__ cnt, const int* __restrict__ bsum,
    int* __restrict__ rowptr, int* __restrict__ cursor, int N, int nsb)
{
    const int t = threadIdx.x, b = blockIdx.x;
    __shared__ int sboff;
    if (t == 0) {
        int r = 0;
        for (int i2 = 0; i2 < b; ++i2) r += bsum[i2];
        sboff = r;
    }
    if (t == 64 && b == nsb - 1) {
        int r = 0;
        for (int i2 = 0; i2 < nsb; ++i2) r += bsum[i2];
        rowptr[N] = r;
    }
    int base = b * 2048 + t * 8;
    int loc[8];
    int s = 0;
#pragma unroll
    for (int j = 0; j < 8; ++j) {
        int idx = base + j;
        loc[j] = (idx < N) ? cnt[idx] : 0;
        s += loc[j];
    }
    __shared__ int part[256];
    part[t] = s;
    __syncthreads();
    for (int off = 1; off < 256; off <<= 1) {
        int v = (t >= off) ? part[t - off] : 0;
        __syncthreads();
        part[t] += v;
        __syncthreads();
    }
    int run = sboff + (t ? part[t - 1] : 0);
#pragma unroll
    for (int j = 0; j < 8; ++j) {
        int idx = base + j;
        if (idx < N) { rowptr[idx] = run; cursor[idx] = run; run += loc[j]; }
    }
}

__global__ __launch_bounds__(256) void k_scatter(
    const int* __restrict__ src, const int* __restrict__ dst,
    int* __restrict__ cursor, int* __restrict__ csr_src, int E)
{
    int e = blockIdx.x * 256 + threadIdx.x;
    if (e < E) {
        int pos = atomicAdd(&cursor[dst[e]], 1);
        csr_src[pos] = src[e];
    }
}

// --- attention: one wave per node, lane owns channels (2l, 2l+1). ----------
__global__ __launch_bounds__(256) void k_attn(
    const f16* __restrict__ Qb, const f16* __restrict__ Kb,
    const f16* __restrict__ Vb,
    const int* __restrict__ rowptr, const int* __restrict__ csr_src,
    f16* __restrict__ attnf, int N)
{
    const int node = blockIdx.x * 4 + (threadIdx.x >> 6);
    const int lane = threadIdx.x & 63;
    if (node >= N) return;
    const int beg = rowptr[node], end = rowptr[node + 1];
    const h2 q2 = ((const h2*)(Qb + (size_t)node * 128))[lane];
    h2 accA = {(f16)0.f, (f16)0.f};
    h2 accB = {(f16)0.f, (f16)0.f};
    float zA = 0.f, zB = 0.f;
    int i = beg;
    for (; i + 3 < end; i += 4) {
        int s0 = csr_src[i], s1 = csr_src[i + 1];
        int s2 = csr_src[i + 2], s3 = csr_src[i + 3];
        h2 k0 = ((const h2*)(Kb + (size_t)s0 * 128))[lane];
        h2 k1 = ((const h2*)(Kb + (size_t)s1 * 128))[lane];
        h2 k2 = ((const h2*)(Kb + (size_t)s2 * 128))[lane];
        h2 k3 = ((const h2*)(Kb + (size_t)s3 * 128))[lane];
        h2 v0 = ((const h2*)(Vb + (size_t)s0 * 128))[lane];
        h2 v1 = ((const h2*)(Vb + (size_t)s1 * 128))[lane];
        h2 v2 = ((const h2*)(Vb + (size_t)s2 * 128))[lane];
        h2 v3 = ((const h2*)(Vb + (size_t)s3 * 128))[lane];
        float p0 = __builtin_amdgcn_fdot2(q2, k0, 0.f, false);
        float p1 = __builtin_amdgcn_fdot2(q2, k1, 0.f, false);
        float p2 = __builtin_amdgcn_fdot2(q2, k2, 0.f, false);
        float p3 = __builtin_amdgcn_fdot2(q2, k3, 0.f, false);
        p0 += __shfl_xor(p0, 4, 8); p1 += __shfl_xor(p1, 4, 8);
        p2 += __shfl_xor(p2, 4, 8); p3 += __shfl_xor(p3, 4, 8);
        p0 += __shfl_xor(p0, 2, 8); p1 += __shfl_xor(p1, 2, 8);
        p2 += __shfl_xor(p2, 2, 8); p3 += __shfl_xor(p3, 2, 8);
        p0 += __shfl_xor(p0, 1, 8); p1 += __shfl_xor(p1, 1, 8);
        p2 += __shfl_xor(p2, 1, 8); p3 += __shfl_xor(p3, 1, 8);
        float sc0 = __expf(fminf(fmaxf(p0 * 0.25f, -5.f), 5.f));
        float sc1 = __expf(fminf(fmaxf(p1 * 0.25f, -5.f), 5.f));
        float sc2 = __expf(fminf(fmaxf(p2 * 0.25f, -5.f), 5.f));
        float sc3 = __expf(fminf(fmaxf(p3 * 0.25f, -5.f), 5.f));
        h2 h0 = {(f16)sc0, (f16)sc0}, h1v = {(f16)sc1, (f16)sc1};
        h2 h2v = {(f16)sc2, (f16)sc2}, h3 = {(f16)sc3, (f16)sc3};
        accA = v0 * h0 + accA;  accB = v1 * h1v + accB;
        accA = v2 * h2v + accA; accB = v3 * h3 + accB;
        zA += sc0 + sc2; zB += sc1 + sc3;
    }
    for (; i < end; ++i) {
        int s0 = csr_src[i];
        h2 k0 = ((const h2*)(Kb + (size_t)s0 * 128))[lane];
        h2 v0 = ((const h2*)(Vb + (size_t)s0 * 128))[lane];
        float p0 = __builtin_amdgcn_fdot2(q2, k0, 0.f, false);
        p0 += __shfl_xor(p0, 4, 8); p0 += __shfl_xor(p0, 2, 8); p0 += __shfl_xor(p0, 1, 8);
        float sc0 = __expf(fminf(fmaxf(p0 * 0.25f, -5.f), 5.f));
        h2 h0 = {(f16)sc0, (f16)sc0};
        accA = v0 * h0 + accA;
        zA += sc0;
    }
    h2 acc2 = accA + accB;
    float z = zA + zB;
    float inv = 1.f / z;
    h2 o2 = {(f16)((float)acc2.x * inv), (f16)((float)acc2.y * inv)};
    int slab = node >> 7, m = (node >> 4) & 7, lr = node & 15;
    int kb = lane >> 4, quad2 = (lane & 15) >> 2, j = (lane & 3) * 2;
    *(h2*)(attnf + (size_t)slab * ND128 +
           (size_t)(((kb * 8 + m) * 64 + lr + 16 * quad2) * 8 + j)) = o2;
}

// --- O-proj: t1 = attn @ WO^T + h + bO -> f16 frag t1b; BN1 sums. ----------
__global__ __launch_bounds__(256) void k_oproj(
    const f16* __restrict__ attnf, const f16* __restrict__ Wob,
    const float* __restrict__ h, const float* __restrict__ bO,
    f16* __restrict__ t1b, float* __restrict__ bn, int N)
{
    __shared__ float csum[128], csq[128];
    const int tid = threadIdx.x, slab = blockIdx.x;
    const int w = tid >> 6, lane = tid & 63;
    if (tid < 128) { csum[tid] = 0.f; csq[tid] = 0.f; }
    __syncthreads();
    const f16* A = attnf + (size_t)slab * ND128;

    h8 bfr[2][4];
#pragma unroll
    for (int nt = 0; nt < 2; ++nt)
#pragma unroll
        for (int kb = 0; kb < 4; ++kb)
            bfr[nt][kb] = *(const h8*)(Wob + (size_t)(((2 * w + nt) * 4 + kb) * 64 + lane) * 8);

    f4 acc[8][2];
    f4 zero = {0.f, 0.f, 0.f, 0.f};
#pragma unroll
    for (int m = 0; m < 8; ++m) { acc[m][0] = zero; acc[m][1] = zero; }
#pragma unroll
    for (int m = 0; m < 8; ++m) {
#pragma unroll
        for (int kb = 0; kb < 4; ++kb) {
            h8 a = *(const h8*)(A + (size_t)((kb * 8 + m) * 64 + lane) * 8);
            acc[m][0] = __builtin_amdgcn_mfma_f32_16x16x32_f16(bfr[0][kb], a, acc[m][0], 0, 0, 0);
            acc[m][1] = __builtin_amdgcn_mfma_f32_16x16x32_f16(bfr[1][kb], a, acc[m][1], 0, 0, 0);
        }
    }

    const int rl = lane & 15, quad = lane >> 4;
    float4 bo[2];
#pragma unroll
    for (int nt = 0; nt < 2; ++nt)
        bo[nt] = *(const float4*)(bO + w * 32 + nt * 16 + quad * 4);
    float pcs[2][4], pcq[2][4];
#pragma unroll
    for (int nt = 0; nt < 2; ++nt)
#pragma unroll
        for (int r = 0; r < 4; ++r) { pcs[nt][r] = 0.f; pcq[nt][r] = 0.f; }

#pragma unroll
    for (int m = 0; m < 8; ++m) {
        int gr = slab * 128 + m * 16 + rl;
        if (gr < N) {
#pragma unroll
            for (int nt = 0; nt < 2; ++nt) {
                int col0 = w * 32 + nt * 16 + quad * 4;
                float4 hv = *(const float4*)(h + (size_t)gr * 128 + col0);
                float v0 = acc[m][nt][0] + hv.x + bo[nt].x;
                float v1 = acc[m][nt][1] + hv.y + bo[nt].y;
                float v2 = acc[m][nt][2] + hv.z + bo[nt].z;
                float v3 = acc[m][nt][3] + hv.w + bo[nt].w;
                h4 o; o[0] = (f16)v0; o[1] = (f16)v1; o[2] = (f16)v2; o[3] = (f16)v3;
                *(h4*)(t1b + (size_t)slab * ND128 +
                       (size_t)(((w * 8 + m) * 64 + (nt * 2 + (quad >> 1)) * 16 + rl) * 8 +
                                (quad & 1) * 4)) = o;
                pcs[nt][0] += v0; pcq[nt][0] += v0 * v0;
                pcs[nt][1] += v1; pcq[nt][1] += v1 * v1;
                pcs[nt][2] += v2; pcq[nt][2] += v2 * v2;
                pcs[nt][3] += v3; pcq[nt][3] += v3 * v3;
            }
        }
    }
#pragma unroll
    for (int nt = 0; nt < 2; ++nt)
#pragma unroll
        for (int r = 0; r < 4; ++r) {
            float s = pcs[nt][r], q = pcq[nt][r];
            s += __shfl_xor(s, 8, 16); q += __shfl_xor(q, 8, 16);
            s += __shfl_xor(s, 4, 16); q += __shfl_xor(q, 4, 16);
            s += __shfl_xor(s, 2, 16); q += __shfl_xor(q, 2, 16);
            s += __shfl_xor(s, 1, 16); q += __shfl_xor(q, 1, 16);
            if (rl == 0) {
                int cl = w * 32 + nt * 16 + quad * 4 + r;
                atomicAdd(&csum[cl], s);
                atomicAdd(&csq[cl], q);
            }
        }
    __syncthreads();
    if (tid < 128) {
        atomicAdd(bn + tid, csum[tid]);
        atomicAdd(bn + 128 + tid, csq[tid]);
    }
}

// --- fold BN1 into W1/bias. 256 blocks (one per W1 row). -------------------
__global__ __launch_bounds__(128) void k_fold1(
    const float* __restrict__ bn, const float* __restrict__ g1,
    const float* __restrict__ bb1, const float* __restrict__ W1,
    const float* __restrict__ b1, f16* __restrict__ W1b,
    float* __restrict__ badj, float* __restrict__ sfold,
    float* __restrict__ bfold, int N)
{
    const int o = blockIdx.x, i = threadIdx.x;
    float invN = 1.f / (float)N;
    float mu = bn[i] * invN;
    float var = bn[128 + i] * invN - mu * mu;
    float s = g1[i] * rsqrtf(var + 1e-5f);
    float bb = bb1[i] - mu * s;
    if (o == 0) { sfold[i] = s; bfold[i] = bb; }
    float wv = W1[(size_t)o * 128 + i];
    __shared__ float red[128];
    red[i] = wv * bb;
    const int nt = o >> 4, lanelow = o & 15;
    const int kb = i >> 5, quad = (i >> 3) & 3, j = i & 7;
    W1b[(size_t)(((nt * 4 + kb) * 64 + lanelow + 16 * quad) * 8 + j)] = (f16)(wv * s);
    __syncthreads();
#pragma unroll
    for (int off = 64; off; off >>= 1) {
        if (i < off) red[i] += red[i + off];
        __syncthreads();
    }
    if (i == 0) badj[o] = b1[o] + red[0];
}

// --- FFN1: u = relu(t1b @ W1s^T + badj), f16 frag order (K=256 layout). ----
__global__ __launch_bounds__(256) void k_ffn1(
    const f16* __restrict__ t1b, const f16* __restrict__ W1b,
    const float* __restrict__ badj, f16* __restrict__ ub, int N)
{
    const int slab = blockIdx.x, ch = blockIdx.y;
    const int w = threadIdx.x >> 6, lane = threadIdx.x & 63;
    const f16* A = t1b + (size_t)slab * ND128;

    h8 bfr[2][4];
#pragma unroll
    for (int nt = 0; nt < 2; ++nt)
#pragma unroll
        for (int kb = 0; kb < 4; ++kb) {
            int ntg = ch * 8 + 2 * w + nt;
            bfr[nt][kb] = *(const h8*)(W1b + (size_t)((ntg * 4 + kb) * 64 + lane) * 8);
        }

    f4 acc[8][2];
    f4 zero = {0.f, 0.f, 0.f, 0.f};
#pragma unroll
    for (int m = 0; m < 8; ++m) { acc[m][0] = zero; acc[m][1] = zero; }
#pragma unroll
    for (int m = 0; m < 8; ++m) {
#pragma unroll
        for (int kb = 0; kb < 4; ++kb) {
            h8 a = *(const h8*)(A + (size_t)((kb * 8 + m) * 64 + lane) * 8);
            acc[m][0] = __builtin_amdgcn_mfma_f32_16x16x32_f16(bfr[0][kb], a, acc[m][0], 0, 0, 0);
            acc[m][1] = __builtin_amdgcn_mfma_f32_16x16x32_f16(bfr[1][kb], a, acc[m][1], 0, 0, 0);
        }
    }

    const int rl = lane & 15, quad = lane >> 4;
    const int kbu = ch * 4 + w;
    float4 ba[2];
#pragma unroll
    for (int nt = 0; nt < 2; ++nt)
        ba[nt] = *(const float4*)(badj + ch * 128 + w * 32 + nt * 16 + quad * 4);
#pragma unroll
    for (int m = 0; m < 8; ++m) {
        int gr = slab * 128 + m * 16 + rl;
        if (gr < N) {
#pragma unroll
            for (int nt = 0; nt < 2; ++nt) {
                h4 o;
                o[0] = (f16)fmaxf(acc[m][nt][0] + ba[nt].x, 0.f);
                o[1] = (f16)fmaxf(acc[m][nt][1] + ba[nt].y, 0.f);
                o[2] = (f16)fmaxf(acc[m][nt][2] + ba[nt].z, 0.f);
                o[3] = (f16)fmaxf(acc[m][nt][3] + ba[nt].w, 0.f);
                *(h4*)(ub + (size_t)slab * 32768 +
                       (size_t)(((kbu * 8 + m) * 64 + (nt * 2 + (quad >> 1)) * 16 + rl) * 8 +
                                (quad & 1) * 4)) = o;
            }
        }
    }
}

// --- FFN2: t2 = (s1*t1 + b1v + b2) + u @ W2^T; fp32 out; BN2 sums. ---------
__global__ __launch_bounds__(256) void k_ffn2(
    const f16* __restrict__ ub, const f16* __restrict__ W2b,
    const f16* __restrict__ t1b,
    const float* __restrict__ sfold, const float* __restrict__ bfold,
    const float* __restrict__ b2, float* __restrict__ out,
    float* __restrict__ bn, int N)
{
    __shared__ float csum[128], csq[128], sS[128], sB[128];
    const int tid = threadIdx.x, slab = blockIdx.x;
    const int w = tid >> 6, lane = tid & 63;
    if (tid < 128) {
        csum[tid] = 0.f; csq[tid] = 0.f;
        sS[tid] = sfold[tid]; sB[tid] = bfold[tid] + b2[tid];
    }
    __syncthreads();
    const f16* A = ub + (size_t)slab * 32768;
    const f16* T1 = t1b + (size_t)slab * ND128;

    h8 bfr[2][8];
#pragma unroll
    for (int nt = 0; nt < 2; ++nt)
#pragma unroll
        for (int kb = 0; kb < 8; ++kb)
            bfr[nt][kb] = *(const h8*)(W2b + (size_t)(((2 * w + nt) * 8 + kb) * 64 + lane) * 8);

    f4 acc[8][2];
    f4 zero = {0.f, 0.f, 0.f, 0.f};
#pragma unroll
    for (int m = 0; m < 8; ++m) { acc[m][0] = zero; acc[m][1] = zero; }
#pragma unroll
    for (int m = 0; m < 8; ++m) {
#pragma unroll
        for (int kb = 0; kb < 8; ++kb) {
            h8 a = *(const h8*)(A + (size_t)((kb * 8 + m) * 64 + lane) * 8);
            acc[m][0] = __builtin_amdgcn_mfma_f32_16x16x32_f16(bfr[0][kb], a, acc[m][0], 0, 0, 0);
            acc[m][1] = __builtin_amdgcn_mfma_f32_16x16x32_f16(bfr[1][kb], a, acc[m][1], 0, 0, 0);
        }
    }

    const int rl = lane & 15, quad = lane >> 4;
    float pcs[2][4], pcq[2][4];
#pragma unroll
    for (int nt = 0; nt < 2; ++nt)
#pragma unroll
        for (int r = 0; r < 4; ++r) { pcs[nt][r] = 0.f; pcq[nt][r] = 0.f; }

#pragma unroll
    for (int m = 0; m < 8; ++m) {
        int gr = slab * 128 + m * 16 + rl;
        if (gr < N) {
#pragma unroll
            for (int nt = 0; nt < 2; ++nt) {
                int col0 = w * 32 + nt * 16 + quad * 4;
                h4 t1v = *(const h4*)(T1 +
                    (size_t)(((w * 8 + m) * 64 + (nt * 2 + (quad >> 1)) * 16 + rl) * 8 +
                             (quad & 1) * 4));
                float4 ss = *(const float4*)&sS[col0];
                float4 sb = *(const float4*)&sB[col0];
                float4 o;
                o.x = acc[m][nt][0] + fmaf(ss.x, (float)t1v[0], sb.x);
                o.y = acc[m][nt][1] + fmaf(ss.y, (float)t1v[1], sb.y);
                o.z = acc[m][nt][2] + fmaf(ss.z, (float)t1v[2], sb.z);
                o.w = acc[m][nt][3] + fmaf(ss.w, (float)t1v[3], sb.w);
                *(float4*)(out + (size_t)gr * 128 + col0) = o;
                pcs[nt][0] += o.x; pcq[nt][0] += o.x * o.x;
                pcs[nt][1] += o.y; pcq[nt][1] += o.y * o.y;
                pcs[nt][2] += o.z; pcq[nt][2] += o.z * o.z;
                pcs[nt][3] += o.w; pcq[nt][3] += o.w * o.w;
            }
        }
    }
#pragma unroll
    for (int nt = 0; nt < 2; ++nt)
#pragma unroll
        for (int r = 0; r < 4; ++r) {
            float s = pcs[nt][r], q = pcq[nt][r];
            s += __shfl_xor(s, 8, 16); q += __shfl_xor(q, 8, 16);
            s += __shfl_xor(s, 4, 16); q += __shfl_xor(q, 4, 16);
            s += __shfl_xor(s, 2, 16); q += __shfl_xor(q, 2, 16);
            s += __shfl_xor(s, 1, 16); q += __shfl_xor(q, 1, 16);
            if (rl == 0) {
                int cl = w * 32 + nt * 16 + quad * 4 + r;
                atomicAdd(&csum[cl], s);
                atomicAdd(&csq[cl], q);
            }
        }
    __syncthreads();
    if (tid < 128) {
        atomicAdd(bn + 256 + tid, csum[tid]);
        atomicAdd(bn + 384 + tid, csq[tid]);
    }
}

// --- BN2 normalize in place ------------------------------------------------
__global__ __launch_bounds__(256) void k_bn2(
    float* __restrict__ out, const float* __restrict__ bn,
    const float* __restrict__ g2, const float* __restrict__ bb2, int N)
{
    __shared__ float sS[128], sB[128];
    const int tid = threadIdx.x;
    if (tid < 128) {
        float invN = 1.f / (float)N;
        float mu = bn[256 + tid] * invN;
        float var = bn[384 + tid] * invN - mu * mu;
        float scl = g2[tid] * rsqrtf(var + 1e-5f);
        sS[tid] = scl;
        sB[tid] = bb2[tid] - mu * scl;
    }
    __syncthreads();
    size_t idx = (size_t)blockIdx.x * 256 + tid;
    size_t total = (size_t)N * 32;
    if (idx < total) {
        int c0 = (int)((idx * 4) & 127);
        float4 v = *(const float4*)(out + idx * 4);
        v.x = fmaf(v.x, sS[c0 + 0], sB[c0 + 0]);
        v.y = fmaf(v.y, sS[c0 + 1], sB[c0 + 1]);
        v.z = fmaf(v.z, sS[c0 + 2], sB[c0 + 2]);
        v.w = fmaf(v.w, sS[c0 + 3], sB[c0 + 3]);
        *(float4*)(out + idx * 4) = v;
    }
}

extern "C" void kernel_launch(void* const* d_in, const int* in_sizes, int n_in,
                              void* d_out, int out_size, void* d_ws, size_t ws_size,
                              hipStream_t stream)
{
    const float* h   = (const float*)d_in[0];
    const int*   src = (const int*)d_in[1];
    const int*   dst = (const int*)d_in[2];
    const float* WQ  = (const float*)d_in[3];
    const float* WK  = (const float*)d_in[4];
    const float* WV  = (const float*)d_in[5];
    const float* WO  = (const float*)d_in[6];
    const float* bO  = (const float*)d_in[7];
    const float* W1  = (const float*)d_in[8];
    const float* b1  = (const float*)d_in[9];
    const float* W2  = (const float*)d_in[10];
    const float* b2  = (const float*)d_in[11];
    const float* g1  = (const float*)d_in[12];
    const float* bb1 = (const float*)d_in[13];
    const float* g2  = (const float*)d_in[14];
    const float* bb2 = (const float*)d_in[15];
    float* out = (float*)d_out;

    int N = in_sizes[0] / 128;
    int E = in_sizes[1];
    const int slabs = (N + 127) / 128;
    const int nsb = (N + 2047) / 2048;         // scan blocks (~25)
    const size_t B1 = (size_t)slabs * 32768;   // bytes of one f16 N_pad x 128 buffer

    char* Wp = (char*)d_ws;
    f16* hb  = (f16*)Wp;                             // -> attnf after qkv
    f16* Qb  = (f16*)(Wp + B1);
    f16* Kb  = (f16*)(Wp + 2 * B1);
    f16* Vb  = (f16*)(Wp + 3 * B1);
    f16* t1b = (f16*)(Wp + 3 * B1);                  // overlays Vb (dead after attn)
    f16* ub  = (f16*)(Wp + B1);                      // overlays Qb+Kb (dead after attn)
    const size_t base = 4 * B1;
    f16* Wqb = (f16*)(Wp + base);
    f16* Wkb = (f16*)(Wp + base + 32768);
    f16* Wvb = (f16*)(Wp + base + 65536);
    f16* Wob = (f16*)(Wp + base + 98304);
    f16* W1b = (f16*)(Wp + base + 131072);
    f16* W2b = (f16*)(Wp + base + 196608);
    float* badj  = (float*)(Wp + base + 262144);
    float* sfold = (float*)(Wp + base + 263168);
    float* bfold = (float*)(Wp + base + 263680);
    float* bn    = (float*)(Wp + base + 264192);     // 512 floats (zeroed in prep)
    int* cursor  = (int*)(Wp + base + 266240);       // N ints (zeroed in prep)
    int* rowptr  = (int*)(Wp + base + 266240 + (size_t)N * 4);
    int* csr     = (int*)(Wp + base + 266240 + (size_t)N * 8 + 8);
    int* bsum    = (int*)((char*)csr + (size_t)E * 4);

    k_prep<<<slabs, 256, 0, stream>>>(h, hb, WQ, WK, WV, WO, W2,
                                      Wqb, Wkb, Wvb, Wob, W2b, bn, cursor, N);
    k_qkv<<<dim3(slabs, 3), 256, 0, stream>>>(hb, Wqb, Wkb, Wvb, Qb, Kb, Vb, N);
    k_hist<<<(E + 255) / 256, 256, 0, stream>>>(dst, cursor, E);
    k_scanA<<<nsb, 256, 0, stream>>>(cursor, bsum, N);
    k_scanC<<<nsb, 256, 0, stream>>>(cursor, bsum, rowptr, cursor, N, nsb);
    k_scatter<<<(E + 255) / 256, 256, 0, stream>>>(src, dst, cursor, csr, E);
    k_attn<<<(N + 3) / 4, 256, 0, stream>>>(Qb, Kb, Vb, rowptr, csr, hb, N);
    k_oproj<<<slabs, 256, 0, stream>>>(hb, Wob, h, bO, t1b, bn, N);
    k_fold1<<<256, 128, 0, stream>>>(bn, g1, bb1, W1, b1, W1b, badj, sfold, bfold, N);
    k_ffn1<<<dim3(slabs, 2), 256, 0, stream>>>(t1b, W1b, badj, ub, N);
    k_ffn2<<<slabs, 256, 0, stream>>>(ub, W2b, t1b, sfold, bfold, b2, out, bn, N);
    k_bn2<<<(int)(((size_t)N * 32 + 255) / 256), 256, 0, stream>>>(out, bn, g2, bb2, N);
}